// Round 8
// baseline (927.591 us; speedup 1.0000x reference)
//
#include <hip/hip_runtime.h>
#include <stdint.h>
#include <math.h>

typedef __bf16 bf16;
typedef __attribute__((ext_vector_type(8))) __bf16 bf16x8;
typedef __attribute__((ext_vector_type(16))) float f32x16;

#define AS1 __attribute__((address_space(1)))
#define AS3 __attribute__((address_space(3)))

__device__ __forceinline__ void glds16(const void* g, void* l) {
    __builtin_amdgcn_global_load_lds((const AS1 uint32_t*)g, (AS3 uint32_t*)l, 16, 0, 0);
}

// Fragment-tile (FT) layout for X[M,K]: tile (rb=r>>5, ks=k>>4) is 512 elems:
// addr = (rb*(K/16)+ks)*512 + (((k>>3)&1)*32 + (r&31))*8 + (k&7).
// A wave's MFMA fragment = 1KB contiguous -> coalesced staging loads.
//
// SESSION LEDGER (gemm K-loop): R0 m97-2blk=187us/Mfma32 (ANCHOR); R1 8ph=194/31;
// R2 fat=206/28; R3 m201=227/26; R4 3blk=195/31+writeamp; R6 hybrid B-reg=204/29.
// K-loop CLOSED: ~31% MfmaUtil plateau, no pipe >50%, unmoved by TLP or any
// source-level pipelining. R7 norm-fusion: 945->913 (matched prediction).
// R8: dispatch-count fusion only -- cast_x folded into mode-1 staging (fp32
// read+cvt+ds_write, same FT slots); 6 setup dispatches -> 1 k_prep.

// ---------- device helpers for weight transforms ---------------------------
__device__ __forceinline__ void wtransF_body(int a, const float* __restrict__ W,
                                             int K, int N, bf16* __restrict__ Wt) {
    int j = a & 7, c64 = (a >> 3) & 63, tile = a >> 9;
    int m32 = c64 & 31, kh = c64 >> 5;
    int TK = K >> 4;
    int rblk = tile / TK, ks = tile - rblk * TK;
    int n = rblk * 32 + m32, k = ks * 16 + kh * 8 + j;
    Wt[a] = (bf16)W[(size_t)k * N + n];
}

__device__ __forceinline__ void wtransI_body(int a, const float* __restrict__ Wl,
                                             const float* __restrict__ Wr,
                                             int K, int F, bf16* __restrict__ Bt) {
    int j = a & 7, c64 = (a >> 3) & 63, tile = a >> 9;
    int m32 = c64 & 31, kh = c64 >> 5;
    int TK = K >> 4;
    int rblk = tile / TK, ks = tile - rblk * TK;
    int n = rblk * 32 + m32, k = ks * 16 + kh * 8 + j;
    int f = n >> 1;
    float v = (n & 1) ? Wr[(size_t)k * F + f] : Wl[(size_t)k * F + f];
    Bt[a] = (bf16)v;
}

// ---------- one-shot prep: ssq zero + all weight transforms + edge setup ---
// Block ranges (all independent):
//   [0,384)            zero ssq (12*B floats = 3*B float4, B=32768)
//   [384,640)          wtransF  W1 -> Wt1   (65536 elems)
//   [640,4736)         wtransI  Wl2/Wr2 -> Wt2 (1048576)
//   [4736,5760)        wtransI  Wl3/Wr3 -> Wt3 (262144)
//   [5760,6272)        wtransI  Wl4/Wr4 -> Wt4 (131072)
//   6272               k_setup (thread 0)
__global__ __launch_bounds__(256) void k_prep(
    const int* __restrict__ ei, float* __restrict__ gmat,
    const float* __restrict__ W1,
    const float* __restrict__ Wl2, const float* __restrict__ Wr2,
    const float* __restrict__ Wl3, const float* __restrict__ Wr3,
    const float* __restrict__ Wl4, const float* __restrict__ Wr4,
    bf16* __restrict__ Wt1, bf16* __restrict__ Wt2,
    bf16* __restrict__ Wt3, bf16* __restrict__ Wt4,
    float4* __restrict__ ssqz) {
    int b = blockIdx.x, t = threadIdx.x;
    if (b < 384) {
        int i = b * 256 + t;
        if (i < 3 * 32768) ssqz[i] = make_float4(0.f, 0.f, 0.f, 0.f);
        return;
    }
    b -= 384;
    if (b < 256) { wtransF_body(b * 256 + t, W1, 64, 1024, Wt1); return; }
    b -= 256;
    if (b < 4096) { wtransI_body(b * 256 + t, Wl2, Wr2, 1024, 512, Wt2); return; }
    b -= 4096;
    if (b < 1024) { wtransI_body(b * 256 + t, Wl3, Wr3, 512, 256, Wt3); return; }
    b -= 1024;
    if (b < 512) { wtransI_body(b * 256 + t, Wl4, Wr4, 256, 256, Wt4); return; }
    if (t != 0) return;
    // ---- edge setup: A_gcn (gmat[0..15]) and M_sage (gmat[16..31]) ----
    bool is64 = true;
    for (int i = 0; i < 12; i++) if (ei[2 * i + 1] != 0) { is64 = false; break; }
    int src[12], dst[12];
    for (int e = 0; e < 12; e++) {
        if (is64) { src[e] = ei[2 * e]; dst[e] = ei[24 + 2 * e]; }
        else      { src[e] = ei[e];     dst[e] = ei[12 + e]; }
    }
    float deg[4] = {1.f, 1.f, 1.f, 1.f};
    for (int e = 0; e < 12; e++) deg[dst[e]] += 1.f;
    float dinv[4];
    for (int n = 0; n < 4; n++) dinv[n] = 1.f / sqrtf(deg[n]);
    float A[16];
    for (int i = 0; i < 16; i++) A[i] = 0.f;
    for (int e = 0; e < 12; e++) A[dst[e] * 4 + src[e]] += dinv[src[e]] * dinv[dst[e]];
    for (int n = 0; n < 4; n++) A[n * 4 + n] += dinv[n] * dinv[n];
    float cnt[4] = {0.f, 0.f, 0.f, 0.f};
    for (int e = 0; e < 12; e++) cnt[dst[e]] += 1.f;
    for (int n = 0; n < 4; n++) cnt[n] = fmaxf(cnt[n], 1.f);
    float Mm[16];
    for (int i = 0; i < 16; i++) Mm[i] = 0.f;
    for (int e = 0; e < 12; e++) Mm[dst[e] * 4 + src[e]] += 1.f;
    for (int n = 0; n < 4; n++)
        for (int m = 0; m < 4; m++) Mm[n * 4 + m] /= cnt[n];
    for (int i = 0; i < 16; i++) { gmat[i] = A[i]; gmat[16 + i] = Mm[i]; }
}

// ---------- MFMA GEMM, 128x256 tile, BK=64, 32x32x16 bf16, FT operands -----
// K-loop = R0 anchor (m97 structure, barrier-staged glds16, 2 blocks/CU).
// mode 1 (GCN, K=64): A = RAW FP32 x [M,64]; staged in-kernel (float4 read +
// cvt + ds_write_b128 into the same FT slots) -- replaces the cast_x pass.
// NORM FUSION: insq = per-row ssq of the INPUT. Row-scaling commutes with
// GEMM; relu(h*inv)=inv*relu(h). Producer stores relu(tot) un-normalized
// (+ ssq of pre-relu tot); consumer scales acc quads by inv_in[row] before
// the node mix.
// mode 2 (SAGE): out = FT(relu(h_un[M,F=N/2])) + atomic ssq of h_un.
__global__ __launch_bounds__(256, 2) void gemm_mfma(
    const bf16* __restrict__ A, int K,
    const bf16* __restrict__ Bt,
    const float* __restrict__ bias,
    bf16* __restrict__ out, int N, int mode,
    const float* __restrict__ gm, float* __restrict__ ssq,
    const float* __restrict__ insq) {
    __shared__ bf16 sA[8192];    // 16 slots (kslot s*4 + rowblk) x 512
    __shared__ bf16 sB[16384];   // 32 slots (kslot s*8 + colblk) x 512
    const int t = threadIdx.x;
    const int lane = t & 63;
    const int w = t >> 6;
    const int wr = w >> 1, wc = w & 1;
    // XCD-aware swizzle (requires gridDim.y % 8 == 0)
    const int lin = blockIdx.x + gridDim.x * blockIdx.y;
    const int C = gridDim.x;
    const int cls = lin & 7;
    const int s0 = lin >> 3;
    const int rpc = gridDim.y >> 3;
    const int sy = s0 / C;
    const int row0 = (cls * rpc + sy) * 128;
    const int col0 = (s0 - sy * C) * 256;
    const int m32 = lane & 31;
    const int kh = lane >> 5;

    f32x16 acc[2][4] = {};

    const int TK = K >> 4;
    const size_t tA  = ((size_t)(row0 >> 5) + w) * TK;
    const size_t tB0 = ((size_t)(col0 >> 5) + w) * TK;
    const size_t tB1 = ((size_t)(col0 >> 5) + w + 4) * TK;
    const int le = lane * 8;

    for (int kb = 0; kb < K; kb += 64) {
        int kt = kb >> 4;
        if (mode == 1) {
            // K=64: single tile. Stage A from fp32 x directly (fused cast_x).
            const float4* xf = (const float4*)A;
            int r = row0 + w * 32 + m32;
#pragma unroll
            for (int s = 0; s < 4; s++) {
                float4 av = xf[(size_t)r * 16 + s * 4 + kh * 2];
                float4 bv = xf[(size_t)r * 16 + s * 4 + kh * 2 + 1];
                bf16x8 o;
                o[0] = (bf16)av.x; o[1] = (bf16)av.y;
                o[2] = (bf16)av.z; o[3] = (bf16)av.w;
                o[4] = (bf16)bv.x; o[5] = (bf16)bv.y;
                o[6] = (bf16)bv.z; o[7] = (bf16)bv.w;
                *(bf16x8*)&sA[(s * 4 + w) * 512 + le] = o;
            }
#pragma unroll
            for (int s = 0; s < 4; s++) {
                glds16(Bt + (tB0 + kt + s) * 512 + le, &sB[(s * 8 + w) * 512]);
                glds16(Bt + (tB1 + kt + s) * 512 + le, &sB[(s * 8 + w + 4) * 512]);
            }
        } else {
#pragma unroll
            for (int s = 0; s < 4; s++) {
                glds16(A  + (tA  + kt + s) * 512 + le, &sA[(s * 4 + w) * 512]);
                glds16(Bt + (tB0 + kt + s) * 512 + le, &sB[(s * 8 + w) * 512]);
                glds16(Bt + (tB1 + kt + s) * 512 + le, &sB[(s * 8 + w + 4) * 512]);
            }
        }
        __syncthreads();
#pragma unroll
        for (int s = 0; s < 4; s++) {
            bf16x8 af[2], bfr[4];
#pragma unroll
            for (int i = 0; i < 2; i++)
                af[i] = *(const bf16x8*)&sA[(s * 4 + 2 * wr + i) * 512 + le];
#pragma unroll
            for (int j = 0; j < 4; j++)
                bfr[j] = *(const bf16x8*)&sB[(s * 8 + 4 * wc + j) * 512 + le];
#pragma unroll
            for (int i = 0; i < 2; i++)
#pragma unroll
                for (int j = 0; j < 4; j++)
                    acc[i][j] = __builtin_amdgcn_mfma_f32_32x32x16_bf16(af[i], bfr[j], acc[i][j], 0, 0, 0);
        }
        __syncthreads();
    }

    float g[16];
#pragma unroll
    for (int q = 0; q < 16; q++) g[q] = gm[q];

    if (mode == 1) {
        // GCN: node mix per reg-quad + bias + ReLU; write FT (next-K = N)
        const int Tn = N >> 4;
#pragma unroll
        for (int i = 0; i < 2; i++) {
            size_t RBo = (size_t)(row0 >> 5) + 2 * wr + i;
#pragma unroll
            for (int j = 0; j < 4; j++) {
                int c = col0 + (4 * wc + j) * 32 + m32;
                size_t tbase = (RBo * Tn + (c >> 4)) * 512;
                int coff = ((c >> 3) & 1) * 32;
                int cj = c & 7;
                float bsv = bias[c];
#pragma unroll
                for (int q = 0; q < 4; q++) {
#pragma unroll
                    for (int n = 0; n < 4; n++) {
                        float v = g[n * 4 + 0] * acc[i][j][q * 4 + 0] +
                                  g[n * 4 + 1] * acc[i][j][q * 4 + 1] +
                                  g[n * 4 + 2] * acc[i][j][q * 4 + 2] +
                                  g[n * 4 + 3] * acc[i][j][q * 4 + 3] + bsv;
                        out[tbase + (size_t)(coff + 4 * kh + 8 * q + n) * 8 + cj] =
                            (bf16)fmaxf(v, 0.f);
                    }
                }
            }
        }
    } else {
        // SAGE: even m32 = Wl col f (mix), odd = Wr col f (self); write FT(F)
        const int F = N >> 1;
        const int Tf = F >> 4;
        const bool ev = ((m32 & 1) == 0);
        const bool hasin = (insq != nullptr);
#pragma unroll
        for (int i = 0; i < 2; i++) {
            size_t RBo = (size_t)(row0 >> 5) + 2 * wr + i;
            int rbAbs = row0 + (2 * wr + i) * 32 + 4 * kh;
#pragma unroll
            for (int q = 0; q < 4; q++) {
                // fused input-norm: per-row inv of the producer's ssq
                float invq[4] = {1.f, 1.f, 1.f, 1.f};
                if (hasin) {
#pragma unroll
                    for (int n = 0; n < 4; n++)
                        invq[n] = 1.f / fmaxf(sqrtf(insq[rbAbs + 8 * q + n]), 1e-12f);
                }
                float ssql[4] = {0.f, 0.f, 0.f, 0.f};
#pragma unroll
                for (int j = 0; j < 4; j++) {
                    int c = col0 + (4 * wc + j) * 32 + m32;
                    int f = c >> 1;
                    size_t tbase = (RBo * Tf + (f >> 4)) * 512;
                    int foff = ((f >> 3) & 1) * 32;
                    int fj = f & 7;
                    float bsv = bias[f];
                    float a_s[4];
#pragma unroll
                    for (int k2 = 0; k2 < 4; k2++)
                        a_s[k2] = acc[i][j][q * 4 + k2] * invq[k2];
                    float mine[4];
                    if (ev) {
#pragma unroll
                        for (int n = 0; n < 4; n++)
                            mine[n] = g[n * 4 + 0] * a_s[0] +
                                      g[n * 4 + 1] * a_s[1] +
                                      g[n * 4 + 2] * a_s[2] +
                                      g[n * 4 + 3] * a_s[3];
                    } else {
#pragma unroll
                        for (int n = 0; n < 4; n++) mine[n] = a_s[n];
                    }
#pragma unroll
                    for (int n = 0; n < 4; n++) {
                        float oth = __shfl_xor(mine[n], 1);
                        float tot = mine[n] + oth + bsv;
                        ssql[n] += tot * tot;
                        if (ev)
                            out[tbase + (size_t)(foff + 4 * kh + 8 * q + n) * 8 + fj] =
                                (bf16)fmaxf(tot, 0.f);   // store relu'd un-normalized
                    }
                }
#pragma unroll
                for (int n = 0; n < 4; n++) {
                    float v = ssql[n];
                    v += __shfl_xor(v, 1); v += __shfl_xor(v, 2);
                    v += __shfl_xor(v, 4); v += __shfl_xor(v, 8);
                    v += __shfl_xor(v, 16);
                    ssql[n] = v;
                }
                if (m32 == 0) {
#pragma unroll
                    for (int n = 0; n < 4; n++)
                        atomicAdd(&ssq[rbAbs + 8 * q + n], ssql[n] * 0.5f);
                }
            }
        }
    }
}

// ---------- final FC (1024->10) + softmax, fused h4 norm+ReLU, FT input ----
// h4 FT[M,256] (T=16), stored relu'd un-normalized; relu(relu(t)*inv) =
// relu(t)*inv so the fused scaling stays exact.
// Element e: rows 4e..4e+3 live in row-block e>>3 at m32 = 4*(e&7)+node.
// lane -> (ks=lane&15, node=lane>>4), jj loop = kh.
// FC feature index = node*256 + ks*16 + jj*8 + c  (node offset! R12 bug).
__global__ __launch_bounds__(256) void fc_softmax(const bf16x8* __restrict__ h,
                                                  const float* __restrict__ ssq4,
                                                  const float* __restrict__ Wfc,
                                                  const float* __restrict__ bfc,
                                                  float* __restrict__ outp) {
    __shared__ float WT[10][1024];
    int t = threadIdx.x;
    for (int i = t; i < 10240; i += 256) { int o = i % 10, k = i / 10; WT[o][k] = Wfc[i]; }
    __syncthreads();
    int wid = t >> 6, lane = t & 63;
    size_t e = (size_t)blockIdx.x * 4 + wid;
    size_t eb8 = e >> 3;
    int eo = (int)(e & 7);
    int ks = lane & 15, node = lane >> 4;
    float inv = 1.f / fmaxf(sqrtf(ssq4[e * 4 + node]), 1e-12f);
    float acc[10];
#pragma unroll
    for (int o = 0; o < 10; o++) acc[o] = 0.f;
#pragma unroll
    for (int jj = 0; jj < 2; jj++) {
        size_t ch = (eb8 * 16 + ks) * 64 + jj * 32 + eo * 4 + node;
        bf16x8 v = h[ch];
        float f[8];
#pragma unroll
        for (int c = 0; c < 8; c++) f[c] = fmaxf((float)v[c] * inv, 0.f);
        int k0 = node * 256 + ks * 16 + jj * 8;
#pragma unroll
        for (int o = 0; o < 10; o++) {
            const float* wr = &WT[o][k0];
            float s = 0.f;
#pragma unroll
            for (int c = 0; c < 8; c++) s += f[c] * wr[c];
            acc[o] += s;
        }
    }
#pragma unroll
    for (int o = 0; o < 10; o++) {
        float v = acc[o];
        v += __shfl_xor(v, 32); v += __shfl_xor(v, 16); v += __shfl_xor(v, 8);
        v += __shfl_xor(v, 4);  v += __shfl_xor(v, 2);  v += __shfl_xor(v, 1);
        acc[o] = v + bfc[o];
    }
    float mx = acc[0];
#pragma unroll
    for (int o = 1; o < 10; o++) mx = fmaxf(mx, acc[o]);
    float sum = 0.f, p[10];
#pragma unroll
    for (int o = 0; o < 10; o++) { p[o] = expf(acc[o] - mx); sum += p[o]; }
    float inv2 = 1.f / sum;
    if (lane < 10) outp[e * 10 + lane] = p[lane] * inv2;
}

// ---------------------------------------------------------------------------
extern "C" void kernel_launch(void* const* d_in, const int* in_sizes, int n_in,
                              void* d_out, int out_size, void* d_ws, size_t ws_size,
                              hipStream_t stream) {
    const float* x   = (const float*)d_in[0];
    const int*   ei  = (const int*)d_in[1];
    const float* W1  = (const float*)d_in[2];
    const float* b1  = (const float*)d_in[3];
    const float* Wl2 = (const float*)d_in[4];
    const float* bl2 = (const float*)d_in[5];
    const float* Wr2 = (const float*)d_in[6];
    const float* Wl3 = (const float*)d_in[7];
    const float* bl3 = (const float*)d_in[8];
    const float* Wr3 = (const float*)d_in[9];
    const float* Wl4 = (const float*)d_in[10];
    const float* bl4 = (const float*)d_in[11];
    const float* Wr4 = (const float*)d_in[12];
    const float* Wfc = (const float*)d_in[13];
    const float* bfc = (const float*)d_in[14];
    float* out = (float*)d_out;

    const int B = 32768;
    char* base = (char*)d_ws;
    float* gmat = (float*)base;
    bf16* Wt1 = (bf16*)(base + 4096);                  // FT [1024 x 64]
    bf16* Wt2 = Wt1 + 1024 * 64;                       // FT [1024 x 1024] interleaved
    bf16* Wt3 = Wt2 + 1024 * 1024;                     // FT [512 x 512]  interleaved
    bf16* Wt4 = Wt3 + 512 * 512;                       // FT [512 x 256]  interleaved
    float* ssqb = (float*)(Wt4 + 512 * 256);           // 12*B floats (all slices)
    char* sl  = (char*)(ssqb + 12 * B);
    size_t fixed = (size_t)(sl - base);

    // per-elem: R1 8192B + R2 4096B = 12288 B (R0 removed -- cast fused)
    int Bs = B;
    while (Bs > 512 && fixed + (size_t)Bs * 12288 > ws_size) Bs >>= 1;
    int nslice = B / Bs;
    int M = Bs * 4;

    bf16* R1 = (bf16*)sl;                       // h1 FT [M,1024]; then h3 FT [M,256]
    bf16* R2 = R1 + (size_t)Bs * 4096;          // h2 FT [M,512]; then h4 FT [M,256]

    // one-shot prep: ssq zero + all weight transforms + edge setup
    hipLaunchKernelGGL(k_prep, dim3(6273), dim3(256), 0, stream,
                       ei, gmat, W1, Wl2, Wr2, Wl3, Wr3, Wl4, Wr4,
                       Wt1, Wt2, Wt3, Wt4, (float4*)ssqb);

    for (int s = 0; s < nslice; s++) {
        const float* xs = x + (size_t)s * Bs * 256;
        float* ssqs = ssqb + (size_t)s * 3 * M;       // disjoint per slice
        // L1 GCN: h1 = relu(mix(x@W1) + b1)  [mode 1]  N=1024, K=64; A = fp32 x
        hipLaunchKernelGGL(gemm_mfma, dim3(4, M / 128), dim3(256), 0, stream,
                           (const bf16*)xs, 64, Wt1, b1, R1, 1024, 1, gmat,
                           (float*)nullptr, (const float*)nullptr);
        // L2 SAGE: relu(h2_un) (F=512) + ssq2  [mode 2]  N=1024, K=1024
        hipLaunchKernelGGL(gemm_mfma, dim3(4, M / 128), dim3(256), 0, stream,
                           R1, 1024, Wt2, bl2, R2, 1024, 2, gmat + 16, ssqs,
                           (const float*)nullptr);
        // L3 SAGE: relu(h3_un) (F=256) into R1, input scaled by inv(ssq2)
        hipLaunchKernelGGL(gemm_mfma, dim3(2, M / 128), dim3(256), 0, stream,
                           R2, 512, Wt3, bl3, R1, 512, 2, gmat + 16, ssqs + M,
                           (const float*)ssqs);
        // L4 SAGE: relu(h4_un) (F=256) into R2, input scaled by inv(ssq3)
        hipLaunchKernelGGL(gemm_mfma, dim3(2, M / 128), dim3(256), 0, stream,
                           R1, 256, Wt4, bl4, R2, 512, 2, gmat + 16, ssqs + 2 * M,
                           (const float*)(ssqs + M));
        // FC + softmax with fused h4 norm (h4 stored relu'd un-normalized)
        hipLaunchKernelGGL(fc_softmax, dim3(Bs / 4), dim3(256), 0, stream,
                           (const bf16x8*)R2, ssqs + 2 * M, Wfc, bfc,
                           out + (size_t)s * Bs * 10);
    }
}

// Round 10
// 912.849 us; speedup vs baseline: 1.0161x; 1.0161x over previous
//
#include <hip/hip_runtime.h>
#include <stdint.h>
#include <math.h>

typedef __bf16 bf16;
typedef __attribute__((ext_vector_type(8))) __bf16 bf16x8;
typedef __attribute__((ext_vector_type(16))) float f32x16;

#define AS1 __attribute__((address_space(1)))
#define AS3 __attribute__((address_space(3)))

__device__ __forceinline__ void glds16(const void* g, void* l) {
    __builtin_amdgcn_global_load_lds((const AS1 uint32_t*)g, (AS3 uint32_t*)l, 16, 0, 0);
}

// Fragment-tile (FT) layout for X[M,K]: tile (rb=r>>5, ks=k>>4) is 512 elems:
// addr = (rb*(K/16)+ks)*512 + (((k>>3)&1)*32 + (r&31))*8 + (k&7).
// A wave's MFMA fragment = 1KB contiguous -> coalesced staging loads.
//
// SESSION LEDGER (gemm K-loop): R0 m97-2blk=187us/Mfma32 (ANCHOR); R1 8ph=194/31;
// R2 fat=206/28; R3 m201=227/26; R4 3blk=195/31+writeamp; R6 hybrid B-reg=204/29.
// K-loop CLOSED at ~31% MfmaUtil plateau. R7 norm-fusion: 945->913 (matched).
// R8 LESSON: a runtime `if(mode)` INSIDE the K-loop cost the mode-2 path
// ~2.5% (191->195.5, VALUBusy +2) -- keep the hot K-loop branch-free.
// R9: split kernels -- gemm_sage (R0-identical K-loop + norm-fused epilogue),
// gemm_gcn (K=64, fused fp32 cast staging). k_prep kept.
// (R9 resubmit: previous bench attempt died on container acquisition, not code.)

// ---------- device helpers for weight transforms ---------------------------
__device__ __forceinline__ void wtransF_body(int a, const float* __restrict__ W,
                                             int K, int N, bf16* __restrict__ Wt) {
    int j = a & 7, c64 = (a >> 3) & 63, tile = a >> 9;
    int m32 = c64 & 31, kh = c64 >> 5;
    int TK = K >> 4;
    int rblk = tile / TK, ks = tile - rblk * TK;
    int n = rblk * 32 + m32, k = ks * 16 + kh * 8 + j;
    Wt[a] = (bf16)W[(size_t)k * N + n];
}

__device__ __forceinline__ void wtransI_body(int a, const float* __restrict__ Wl,
                                             const float* __restrict__ Wr,
                                             int K, int F, bf16* __restrict__ Bt) {
    int j = a & 7, c64 = (a >> 3) & 63, tile = a >> 9;
    int m32 = c64 & 31, kh = c64 >> 5;
    int TK = K >> 4;
    int rblk = tile / TK, ks = tile - rblk * TK;
    int n = rblk * 32 + m32, k = ks * 16 + kh * 8 + j;
    int f = n >> 1;
    float v = (n & 1) ? Wr[(size_t)k * F + f] : Wl[(size_t)k * F + f];
    Bt[a] = (bf16)v;
}

// ---------- one-shot prep: ssq zero + all weight transforms + edge setup ---
__global__ __launch_bounds__(256) void k_prep(
    const int* __restrict__ ei, float* __restrict__ gmat,
    const float* __restrict__ W1,
    const float* __restrict__ Wl2, const float* __restrict__ Wr2,
    const float* __restrict__ Wl3, const float* __restrict__ Wr3,
    const float* __restrict__ Wl4, const float* __restrict__ Wr4,
    bf16* __restrict__ Wt1, bf16* __restrict__ Wt2,
    bf16* __restrict__ Wt3, bf16* __restrict__ Wt4,
    float4* __restrict__ ssqz) {
    int b = blockIdx.x, t = threadIdx.x;
    if (b < 384) {
        int i = b * 256 + t;
        if (i < 3 * 32768) ssqz[i] = make_float4(0.f, 0.f, 0.f, 0.f);
        return;
    }
    b -= 384;
    if (b < 256) { wtransF_body(b * 256 + t, W1, 64, 1024, Wt1); return; }
    b -= 256;
    if (b < 4096) { wtransI_body(b * 256 + t, Wl2, Wr2, 1024, 512, Wt2); return; }
    b -= 4096;
    if (b < 1024) { wtransI_body(b * 256 + t, Wl3, Wr3, 512, 256, Wt3); return; }
    b -= 1024;
    if (b < 512) { wtransI_body(b * 256 + t, Wl4, Wr4, 256, 256, Wt4); return; }
    if (t != 0) return;
    // ---- edge setup: A_gcn (gmat[0..15]) and M_sage (gmat[16..31]) ----
    bool is64 = true;
    for (int i = 0; i < 12; i++) if (ei[2 * i + 1] != 0) { is64 = false; break; }
    int src[12], dst[12];
    for (int e = 0; e < 12; e++) {
        if (is64) { src[e] = ei[2 * e]; dst[e] = ei[24 + 2 * e]; }
        else      { src[e] = ei[e];     dst[e] = ei[12 + e]; }
    }
    float deg[4] = {1.f, 1.f, 1.f, 1.f};
    for (int e = 0; e < 12; e++) deg[dst[e]] += 1.f;
    float dinv[4];
    for (int n = 0; n < 4; n++) dinv[n] = 1.f / sqrtf(deg[n]);
    float A[16];
    for (int i = 0; i < 16; i++) A[i] = 0.f;
    for (int e = 0; e < 12; e++) A[dst[e] * 4 + src[e]] += dinv[src[e]] * dinv[dst[e]];
    for (int n = 0; n < 4; n++) A[n * 4 + n] += dinv[n] * dinv[n];
    float cnt[4] = {0.f, 0.f, 0.f, 0.f};
    for (int e = 0; e < 12; e++) cnt[dst[e]] += 1.f;
    for (int n = 0; n < 4; n++) cnt[n] = fmaxf(cnt[n], 1.f);
    float Mm[16];
    for (int i = 0; i < 16; i++) Mm[i] = 0.f;
    for (int e = 0; e < 12; e++) Mm[dst[e] * 4 + src[e]] += 1.f;
    for (int n = 0; n < 4; n++)
        for (int m = 0; m < 4; m++) Mm[n * 4 + m] /= cnt[n];
    for (int i = 0; i < 16; i++) { gmat[i] = A[i]; gmat[16 + i] = Mm[i]; }
}

// ---------- GCN GEMM (L1): K=64 single tile, fused fp32->bf16 staging ------
// A = raw fp32 x [M,64] (cast_x deleted); same FT slot layout as the staged
// path. Epilogue: node mix + bias + ReLU; write FT with next-K = N.
__global__ __launch_bounds__(256, 2) void gemm_gcn(
    const float* __restrict__ x,
    const bf16* __restrict__ Bt,
    const float* __restrict__ bias,
    bf16* __restrict__ out, int N,
    const float* __restrict__ gm) {
    __shared__ bf16 sA[8192];    // 16 slots (kslot s*4 + rowblk) x 512
    __shared__ bf16 sB[16384];   // 32 slots (kslot s*8 + colblk) x 512
    const int t = threadIdx.x;
    const int lane = t & 63;
    const int w = t >> 6;
    const int wr = w >> 1, wc = w & 1;
    const int lin = blockIdx.x + gridDim.x * blockIdx.y;
    const int C = gridDim.x;
    const int cls = lin & 7;
    const int s0 = lin >> 3;
    const int rpc = gridDim.y >> 3;
    const int sy = s0 / C;
    const int row0 = (cls * rpc + sy) * 128;
    const int col0 = (s0 - sy * C) * 256;
    const int m32 = lane & 31;
    const int kh = lane >> 5;

    f32x16 acc[2][4] = {};

    const int TK = 4;   // K=64
    const size_t tB0 = ((size_t)(col0 >> 5) + w) * TK;
    const size_t tB1 = ((size_t)(col0 >> 5) + w + 4) * TK;
    const int le = lane * 8;

    {
        const float4* xf = (const float4*)x;
        int r = row0 + w * 32 + m32;
#pragma unroll
        for (int s = 0; s < 4; s++) {
            float4 av = xf[(size_t)r * 16 + s * 4 + kh * 2];
            float4 bv = xf[(size_t)r * 16 + s * 4 + kh * 2 + 1];
            bf16x8 o;
            o[0] = (bf16)av.x; o[1] = (bf16)av.y;
            o[2] = (bf16)av.z; o[3] = (bf16)av.w;
            o[4] = (bf16)bv.x; o[5] = (bf16)bv.y;
            o[6] = (bf16)bv.z; o[7] = (bf16)bv.w;
            *(bf16x8*)&sA[(s * 4 + w) * 512 + le] = o;
        }
#pragma unroll
        for (int s = 0; s < 4; s++) {
            glds16(Bt + (tB0 + s) * 512 + le, &sB[(s * 8 + w) * 512]);
            glds16(Bt + (tB1 + s) * 512 + le, &sB[(s * 8 + w + 4) * 512]);
        }
        __syncthreads();
#pragma unroll
        for (int s = 0; s < 4; s++) {
            bf16x8 af[2], bfr[4];
#pragma unroll
            for (int i = 0; i < 2; i++)
                af[i] = *(const bf16x8*)&sA[(s * 4 + 2 * wr + i) * 512 + le];
#pragma unroll
            for (int j = 0; j < 4; j++)
                bfr[j] = *(const bf16x8*)&sB[(s * 8 + 4 * wc + j) * 512 + le];
#pragma unroll
            for (int i = 0; i < 2; i++)
#pragma unroll
                for (int j = 0; j < 4; j++)
                    acc[i][j] = __builtin_amdgcn_mfma_f32_32x32x16_bf16(af[i], bfr[j], acc[i][j], 0, 0, 0);
        }
    }

    float g[16];
#pragma unroll
    for (int q = 0; q < 16; q++) g[q] = gm[q];

    const int Tn = N >> 4;
#pragma unroll
    for (int i = 0; i < 2; i++) {
        size_t RBo = (size_t)(row0 >> 5) + 2 * wr + i;
#pragma unroll
        for (int j = 0; j < 4; j++) {
            int c = col0 + (4 * wc + j) * 32 + m32;
            size_t tbase = (RBo * Tn + (c >> 4)) * 512;
            int coff = ((c >> 3) & 1) * 32;
            int cj = c & 7;
            float bsv = bias[c];
#pragma unroll
            for (int q = 0; q < 4; q++) {
#pragma unroll
                for (int n = 0; n < 4; n++) {
                    float v = g[n * 4 + 0] * acc[i][j][q * 4 + 0] +
                              g[n * 4 + 1] * acc[i][j][q * 4 + 1] +
                              g[n * 4 + 2] * acc[i][j][q * 4 + 2] +
                              g[n * 4 + 3] * acc[i][j][q * 4 + 3] + bsv;
                    out[tbase + (size_t)(coff + 4 * kh + 8 * q + n) * 8 + cj] =
                        (bf16)fmaxf(v, 0.f);
                }
            }
        }
    }
}

// ---------- SAGE GEMM: 128x256 tile, BK=64, R0-identical branch-free K-loop -
// NORM FUSION: insq = per-row ssq of the INPUT (nullptr => no scaling).
// Row-scaling commutes with GEMM; relu(h*inv)=inv*relu(h). Producer stores
// relu(tot) un-normalized (+ ssq of pre-relu tot); consumer scales acc quads
// by inv_in[row] before the node mix.
__global__ __launch_bounds__(256, 2) void gemm_sage(
    const bf16* __restrict__ A, int K,
    const bf16* __restrict__ Bt,
    const float* __restrict__ bias,
    bf16* __restrict__ out, int N,
    const float* __restrict__ gm, float* __restrict__ ssq,
    const float* __restrict__ insq) {
    __shared__ bf16 sA[8192];    // 16 slots (kslot s*4 + rowblk) x 512
    __shared__ bf16 sB[16384];   // 32 slots (kslot s*8 + colblk) x 512
    const int t = threadIdx.x;
    const int lane = t & 63;
    const int w = t >> 6;
    const int wr = w >> 1, wc = w & 1;
    const int lin = blockIdx.x + gridDim.x * blockIdx.y;
    const int C = gridDim.x;
    const int cls = lin & 7;
    const int s0 = lin >> 3;
    const int rpc = gridDim.y >> 3;
    const int sy = s0 / C;
    const int row0 = (cls * rpc + sy) * 128;
    const int col0 = (s0 - sy * C) * 256;
    const int m32 = lane & 31;
    const int kh = lane >> 5;

    f32x16 acc[2][4] = {};

    const int TK = K >> 4;
    const size_t tA  = ((size_t)(row0 >> 5) + w) * TK;
    const size_t tB0 = ((size_t)(col0 >> 5) + w) * TK;
    const size_t tB1 = ((size_t)(col0 >> 5) + w + 4) * TK;
    const int le = lane * 8;

    for (int kb = 0; kb < K; kb += 64) {
        int kt = kb >> 4;
#pragma unroll
        for (int s = 0; s < 4; s++) {
            glds16(A  + (tA  + kt + s) * 512 + le, &sA[(s * 4 + w) * 512]);
            glds16(Bt + (tB0 + kt + s) * 512 + le, &sB[(s * 8 + w) * 512]);
            glds16(Bt + (tB1 + kt + s) * 512 + le, &sB[(s * 8 + w + 4) * 512]);
        }
        __syncthreads();
#pragma unroll
        for (int s = 0; s < 4; s++) {
            bf16x8 af[2], bfr[4];
#pragma unroll
            for (int i = 0; i < 2; i++)
                af[i] = *(const bf16x8*)&sA[(s * 4 + 2 * wr + i) * 512 + le];
#pragma unroll
            for (int j = 0; j < 4; j++)
                bfr[j] = *(const bf16x8*)&sB[(s * 8 + 4 * wc + j) * 512 + le];
#pragma unroll
            for (int i = 0; i < 2; i++)
#pragma unroll
                for (int j = 0; j < 4; j++)
                    acc[i][j] = __builtin_amdgcn_mfma_f32_32x32x16_bf16(af[i], bfr[j], acc[i][j], 0, 0, 0);
        }
        __syncthreads();
    }

    float g[16];
#pragma unroll
    for (int q = 0; q < 16; q++) g[q] = gm[q];

    const int F = N >> 1;
    const int Tf = F >> 4;
    const bool ev = ((m32 & 1) == 0);
    const bool hasin = (insq != nullptr);
#pragma unroll
    for (int i = 0; i < 2; i++) {
        size_t RBo = (size_t)(row0 >> 5) + 2 * wr + i;
        int rbAbs = row0 + (2 * wr + i) * 32 + 4 * kh;
#pragma unroll
        for (int q = 0; q < 4; q++) {
            // fused input-norm: per-row inv of the producer's ssq
            float invq[4] = {1.f, 1.f, 1.f, 1.f};
            if (hasin) {
#pragma unroll
                for (int n = 0; n < 4; n++)
                    invq[n] = 1.f / fmaxf(sqrtf(insq[rbAbs + 8 * q + n]), 1e-12f);
            }
            float ssql[4] = {0.f, 0.f, 0.f, 0.f};
#pragma unroll
            for (int j = 0; j < 4; j++) {
                int c = col0 + (4 * wc + j) * 32 + m32;
                int f = c >> 1;
                size_t tbase = (RBo * Tf + (f >> 4)) * 512;
                int foff = ((f >> 3) & 1) * 32;
                int fj = f & 7;
                float bsv = bias[f];
                float a_s[4];
#pragma unroll
                for (int k2 = 0; k2 < 4; k2++)
                    a_s[k2] = acc[i][j][q * 4 + k2] * invq[k2];
                float mine[4];
                if (ev) {
#pragma unroll
                    for (int n = 0; n < 4; n++)
                        mine[n] = g[n * 4 + 0] * a_s[0] +
                                  g[n * 4 + 1] * a_s[1] +
                                  g[n * 4 + 2] * a_s[2] +
                                  g[n * 4 + 3] * a_s[3];
                } else {
#pragma unroll
                    for (int n = 0; n < 4; n++) mine[n] = a_s[n];
                }
#pragma unroll
                for (int n = 0; n < 4; n++) {
                    float oth = __shfl_xor(mine[n], 1);
                    float tot = mine[n] + oth + bsv;
                    ssql[n] += tot * tot;
                    if (ev)
                        out[tbase + (size_t)(foff + 4 * kh + 8 * q + n) * 8 + fj] =
                            (bf16)fmaxf(tot, 0.f);   // store relu'd un-normalized
                }
            }
#pragma unroll
            for (int n = 0; n < 4; n++) {
                float v = ssql[n];
                v += __shfl_xor(v, 1); v += __shfl_xor(v, 2);
                v += __shfl_xor(v, 4); v += __shfl_xor(v, 8);
                v += __shfl_xor(v, 16);
                ssql[n] = v;
            }
            if (m32 == 0) {
#pragma unroll
                for (int n = 0; n < 4; n++)
                    atomicAdd(&ssq[rbAbs + 8 * q + n], ssql[n] * 0.5f);
            }
        }
    }
}

// ---------- final FC (1024->10) + softmax, fused h4 norm+ReLU, FT input ----
// h4 FT[M,256] (T=16), stored relu'd un-normalized; relu(relu(t)*inv) =
// relu(t)*inv so the fused scaling stays exact.
// Element e: rows 4e..4e+3 live in row-block e>>3 at m32 = 4*(e&7)+node.
// lane -> (ks=lane&15, node=lane>>4), jj loop = kh.
// FC feature index = node*256 + ks*16 + jj*8 + c  (node offset! R12 bug).
__global__ __launch_bounds__(256) void fc_softmax(const bf16x8* __restrict__ h,
                                                  const float* __restrict__ ssq4,
                                                  const float* __restrict__ Wfc,
                                                  const float* __restrict__ bfc,
                                                  float* __restrict__ outp) {
    __shared__ float WT[10][1024];
    int t = threadIdx.x;
    for (int i = t; i < 10240; i += 256) { int o = i % 10, k = i / 10; WT[o][k] = Wfc[i]; }
    __syncthreads();
    int wid = t >> 6, lane = t & 63;
    size_t e = (size_t)blockIdx.x * 4 + wid;
    size_t eb8 = e >> 3;
    int eo = (int)(e & 7);
    int ks = lane & 15, node = lane >> 4;
    float inv = 1.f / fmaxf(sqrtf(ssq4[e * 4 + node]), 1e-12f);
    float acc[10];
#pragma unroll
    for (int o = 0; o < 10; o++) acc[o] = 0.f;
#pragma unroll
    for (int jj = 0; jj < 2; jj++) {
        size_t ch = (eb8 * 16 + ks) * 64 + jj * 32 + eo * 4 + node;
        bf16x8 v = h[ch];
        float f[8];
#pragma unroll
        for (int c = 0; c < 8; c++) f[c] = fmaxf((float)v[c] * inv, 0.f);
        int k0 = node * 256 + ks * 16 + jj * 8;
#pragma unroll
        for (int o = 0; o < 10; o++) {
            const float* wr = &WT[o][k0];
            float s = 0.f;
#pragma unroll
            for (int c = 0; c < 8; c++) s += f[c] * wr[c];
            acc[o] += s;
        }
    }
#pragma unroll
    for (int o = 0; o < 10; o++) {
        float v = acc[o];
        v += __shfl_xor(v, 32); v += __shfl_xor(v, 16); v += __shfl_xor(v, 8);
        v += __shfl_xor(v, 4);  v += __shfl_xor(v, 2);  v += __shfl_xor(v, 1);
        acc[o] = v + bfc[o];
    }
    float mx = acc[0];
#pragma unroll
    for (int o = 1; o < 10; o++) mx = fmaxf(mx, acc[o]);
    float sum = 0.f, p[10];
#pragma unroll
    for (int o = 0; o < 10; o++) { p[o] = expf(acc[o] - mx); sum += p[o]; }
    float inv2 = 1.f / sum;
    if (lane < 10) outp[e * 10 + lane] = p[lane] * inv2;
}

// ---------------------------------------------------------------------------
extern "C" void kernel_launch(void* const* d_in, const int* in_sizes, int n_in,
                              void* d_out, int out_size, void* d_ws, size_t ws_size,
                              hipStream_t stream) {
    const float* x   = (const float*)d_in[0];
    const int*   ei  = (const int*)d_in[1];
    const float* W1  = (const float*)d_in[2];
    const float* b1  = (const float*)d_in[3];
    const float* Wl2 = (const float*)d_in[4];
    const float* bl2 = (const float*)d_in[5];
    const float* Wr2 = (const float*)d_in[6];
    const float* Wl3 = (const float*)d_in[7];
    const float* bl3 = (const float*)d_in[8];
    const float* Wr3 = (const float*)d_in[9];
    const float* Wl4 = (const float*)d_in[10];
    const float* bl4 = (const float*)d_in[11];
    const float* Wr4 = (const float*)d_in[12];
    const float* Wfc = (const float*)d_in[13];
    const float* bfc = (const float*)d_in[14];
    float* out = (float*)d_out;

    const int B = 32768;
    char* base = (char*)d_ws;
    float* gmat = (float*)base;
    bf16* Wt1 = (bf16*)(base + 4096);                  // FT [1024 x 64]
    bf16* Wt2 = Wt1 + 1024 * 64;                       // FT [1024 x 1024] interleaved
    bf16* Wt3 = Wt2 + 1024 * 1024;                     // FT [512 x 512]  interleaved
    bf16* Wt4 = Wt3 + 512 * 512;                       // FT [512 x 256]  interleaved
    float* ssqb = (float*)(Wt4 + 512 * 256);           // 12*B floats (all slices)
    char* sl  = (char*)(ssqb + 12 * B);
    size_t fixed = (size_t)(sl - base);

    // per-elem: R1 8192B + R2 4096B = 12288 B
    int Bs = B;
    while (Bs > 512 && fixed + (size_t)Bs * 12288 > ws_size) Bs >>= 1;
    int nslice = B / Bs;
    int M = Bs * 4;

    bf16* R1 = (bf16*)sl;                       // h1 FT [M,1024]; then h3 FT [M,256]
    bf16* R2 = R1 + (size_t)Bs * 4096;          // h2 FT [M,512]; then h4 FT [M,256]

    // one-shot prep: ssq zero + all weight transforms + edge setup
    hipLaunchKernelGGL(k_prep, dim3(6273), dim3(256), 0, stream,
                       ei, gmat, W1, Wl2, Wr2, Wl3, Wr3, Wl4, Wr4,
                       Wt1, Wt2, Wt3, Wt4, (float4*)ssqb);

    for (int s = 0; s < nslice; s++) {
        const float* xs = x + (size_t)s * Bs * 256;
        float* ssqs = ssqb + (size_t)s * 3 * M;       // disjoint per slice
        // L1 GCN: h1 = relu(mix(x@W1) + b1)  K=64; A = fp32 x (fused cast)
        hipLaunchKernelGGL(gemm_gcn, dim3(4, M / 128), dim3(256), 0, stream,
                           xs, Wt1, b1, R1, 1024, gmat);
        // L2 SAGE: relu(h2_un) (F=512) + ssq2   N=1024, K=1024
        hipLaunchKernelGGL(gemm_sage, dim3(4, M / 128), dim3(256), 0, stream,
                           R1, 1024, Wt2, bl2, R2, 1024, gmat + 16, ssqs,
                           (const float*)nullptr);
        // L3 SAGE: relu(h3_un) (F=256) into R1, input scaled by inv(ssq2)
        hipLaunchKernelGGL(gemm_sage, dim3(2, M / 128), dim3(256), 0, stream,
                           R2, 512, Wt3, bl3, R1, 512, gmat + 16, ssqs + M,
                           (const float*)ssqs);
        // L4 SAGE: relu(h4_un) (F=256) into R2, input scaled by inv(ssq3)
        hipLaunchKernelGGL(gemm_sage, dim3(2, M / 128), dim3(256), 0, stream,
                           R1, 256, Wt4, bl4, R2, 512, gmat + 16, ssqs + 2 * M,
                           (const float*)(ssqs + M));
        // FC + softmax with fused h4 norm (h4 stored relu'd un-normalized)
        hipLaunchKernelGGL(fc_softmax, dim3(Bs / 4), dim3(256), 0, stream,
                           (const bf16x8*)R2, ssqs + 2 * M, Wfc, bfc,
                           out + (size_t)s * Bs * 10);
    }
}

// Round 11
// 889.779 us; speedup vs baseline: 1.0425x; 1.0259x over previous
//
#include <hip/hip_runtime.h>
#include <stdint.h>
#include <math.h>

typedef __bf16 bf16;
typedef __attribute__((ext_vector_type(8))) __bf16 bf16x8;
typedef __attribute__((ext_vector_type(16))) float f32x16;

#define AS1 __attribute__((address_space(1)))
#define AS3 __attribute__((address_space(3)))

__device__ __forceinline__ void glds16(const void* g, void* l) {
    __builtin_amdgcn_global_load_lds((const AS1 uint32_t*)g, (AS3 uint32_t*)l, 16, 0, 0);
}

// Fragment-tile (FT) layout for X[M,K]: tile (rb=r>>5, ks=k>>4) is 512 elems:
// addr = (rb*(K/16)+ks)*512 + (((k>>3)&1)*32 + (r&31))*8 + (k&7).
// A wave's MFMA fragment = 1KB contiguous -> coalesced staging loads.
//
// SESSION LEDGER (gemm K-loop): R0 m97-2blk=187us/Mfma32 (ANCHOR); R1 8ph=194/31;
// R2 fat=206/28; R3 m201=227/26; R4 3blk=195/31+writeamp; R6 hybrid B-reg=204/29.
// K-loop CLOSED at ~31% MfmaUtil plateau (no pipe >50%, unmoved by TLP or
// source pipelining). R7 norm-fusion 945->913 (matched). R8: in-loop mode
// branch cost sage 2.5% -> R9/R10 kernel split restored 191us (matched; total
// 912.8, session best). R11: fc_softmax grid-stride -- 4096 blocks/slice each
// staging 40KB Wfc (164MB redundant L2 reads) -> 512 blocks x 8 elems/wave.

// ---------- device helpers for weight transforms ---------------------------
__device__ __forceinline__ void wtransF_body(int a, const float* __restrict__ W,
                                             int K, int N, bf16* __restrict__ Wt) {
    int j = a & 7, c64 = (a >> 3) & 63, tile = a >> 9;
    int m32 = c64 & 31, kh = c64 >> 5;
    int TK = K >> 4;
    int rblk = tile / TK, ks = tile - rblk * TK;
    int n = rblk * 32 + m32, k = ks * 16 + kh * 8 + j;
    Wt[a] = (bf16)W[(size_t)k * N + n];
}

__device__ __forceinline__ void wtransI_body(int a, const float* __restrict__ Wl,
                                             const float* __restrict__ Wr,
                                             int K, int F, bf16* __restrict__ Bt) {
    int j = a & 7, c64 = (a >> 3) & 63, tile = a >> 9;
    int m32 = c64 & 31, kh = c64 >> 5;
    int TK = K >> 4;
    int rblk = tile / TK, ks = tile - rblk * TK;
    int n = rblk * 32 + m32, k = ks * 16 + kh * 8 + j;
    int f = n >> 1;
    float v = (n & 1) ? Wr[(size_t)k * F + f] : Wl[(size_t)k * F + f];
    Bt[a] = (bf16)v;
}

// ---------- one-shot prep: ssq zero + all weight transforms + edge setup ---
__global__ __launch_bounds__(256) void k_prep(
    const int* __restrict__ ei, float* __restrict__ gmat,
    const float* __restrict__ W1,
    const float* __restrict__ Wl2, const float* __restrict__ Wr2,
    const float* __restrict__ Wl3, const float* __restrict__ Wr3,
    const float* __restrict__ Wl4, const float* __restrict__ Wr4,
    bf16* __restrict__ Wt1, bf16* __restrict__ Wt2,
    bf16* __restrict__ Wt3, bf16* __restrict__ Wt4,
    float4* __restrict__ ssqz) {
    int b = blockIdx.x, t = threadIdx.x;
    if (b < 384) {
        int i = b * 256 + t;
        if (i < 3 * 32768) ssqz[i] = make_float4(0.f, 0.f, 0.f, 0.f);
        return;
    }
    b -= 384;
    if (b < 256) { wtransF_body(b * 256 + t, W1, 64, 1024, Wt1); return; }
    b -= 256;
    if (b < 4096) { wtransI_body(b * 256 + t, Wl2, Wr2, 1024, 512, Wt2); return; }
    b -= 4096;
    if (b < 1024) { wtransI_body(b * 256 + t, Wl3, Wr3, 512, 256, Wt3); return; }
    b -= 1024;
    if (b < 512) { wtransI_body(b * 256 + t, Wl4, Wr4, 256, 256, Wt4); return; }
    if (t != 0) return;
    // ---- edge setup: A_gcn (gmat[0..15]) and M_sage (gmat[16..31]) ----
    bool is64 = true;
    for (int i = 0; i < 12; i++) if (ei[2 * i + 1] != 0) { is64 = false; break; }
    int src[12], dst[12];
    for (int e = 0; e < 12; e++) {
        if (is64) { src[e] = ei[2 * e]; dst[e] = ei[24 + 2 * e]; }
        else      { src[e] = ei[e];     dst[e] = ei[12 + e]; }
    }
    float deg[4] = {1.f, 1.f, 1.f, 1.f};
    for (int e = 0; e < 12; e++) deg[dst[e]] += 1.f;
    float dinv[4];
    for (int n = 0; n < 4; n++) dinv[n] = 1.f / sqrtf(deg[n]);
    float A[16];
    for (int i = 0; i < 16; i++) A[i] = 0.f;
    for (int e = 0; e < 12; e++) A[dst[e] * 4 + src[e]] += dinv[src[e]] * dinv[dst[e]];
    for (int n = 0; n < 4; n++) A[n * 4 + n] += dinv[n] * dinv[n];
    float cnt[4] = {0.f, 0.f, 0.f, 0.f};
    for (int e = 0; e < 12; e++) cnt[dst[e]] += 1.f;
    for (int n = 0; n < 4; n++) cnt[n] = fmaxf(cnt[n], 1.f);
    float Mm[16];
    for (int i = 0; i < 16; i++) Mm[i] = 0.f;
    for (int e = 0; e < 12; e++) Mm[dst[e] * 4 + src[e]] += 1.f;
    for (int n = 0; n < 4; n++)
        for (int m = 0; m < 4; m++) Mm[n * 4 + m] /= cnt[n];
    for (int i = 0; i < 16; i++) { gmat[i] = A[i]; gmat[16 + i] = Mm[i]; }
}

// ---------- GCN GEMM (L1): K=64 single tile, fused fp32->bf16 staging ------
// A = raw fp32 x [M,64] (cast_x deleted); same FT slot layout as the staged
// path. Epilogue: node mix + bias + ReLU; write FT with next-K = N.
__global__ __launch_bounds__(256, 2) void gemm_gcn(
    const float* __restrict__ x,
    const bf16* __restrict__ Bt,
    const float* __restrict__ bias,
    bf16* __restrict__ out, int N,
    const float* __restrict__ gm) {
    __shared__ bf16 sA[8192];    // 16 slots (kslot s*4 + rowblk) x 512
    __shared__ bf16 sB[16384];   // 32 slots (kslot s*8 + colblk) x 512
    const int t = threadIdx.x;
    const int lane = t & 63;
    const int w = t >> 6;
    const int wr = w >> 1, wc = w & 1;
    const int lin = blockIdx.x + gridDim.x * blockIdx.y;
    const int C = gridDim.x;
    const int cls = lin & 7;
    const int s0 = lin >> 3;
    const int rpc = gridDim.y >> 3;
    const int sy = s0 / C;
    const int row0 = (cls * rpc + sy) * 128;
    const int col0 = (s0 - sy * C) * 256;
    const int m32 = lane & 31;
    const int kh = lane >> 5;

    f32x16 acc[2][4] = {};

    const int TK = 4;   // K=64
    const size_t tB0 = ((size_t)(col0 >> 5) + w) * TK;
    const size_t tB1 = ((size_t)(col0 >> 5) + w + 4) * TK;
    const int le = lane * 8;

    {
        const float4* xf = (const float4*)x;
        int r = row0 + w * 32 + m32;
#pragma unroll
        for (int s = 0; s < 4; s++) {
            float4 av = xf[(size_t)r * 16 + s * 4 + kh * 2];
            float4 bv = xf[(size_t)r * 16 + s * 4 + kh * 2 + 1];
            bf16x8 o;
            o[0] = (bf16)av.x; o[1] = (bf16)av.y;
            o[2] = (bf16)av.z; o[3] = (bf16)av.w;
            o[4] = (bf16)bv.x; o[5] = (bf16)bv.y;
            o[6] = (bf16)bv.z; o[7] = (bf16)bv.w;
            *(bf16x8*)&sA[(s * 4 + w) * 512 + le] = o;
        }
#pragma unroll
        for (int s = 0; s < 4; s++) {
            glds16(Bt + (tB0 + s) * 512 + le, &sB[(s * 8 + w) * 512]);
            glds16(Bt + (tB1 + s) * 512 + le, &sB[(s * 8 + w + 4) * 512]);
        }
        __syncthreads();
#pragma unroll
        for (int s = 0; s < 4; s++) {
            bf16x8 af[2], bfr[4];
#pragma unroll
            for (int i = 0; i < 2; i++)
                af[i] = *(const bf16x8*)&sA[(s * 4 + 2 * wr + i) * 512 + le];
#pragma unroll
            for (int j = 0; j < 4; j++)
                bfr[j] = *(const bf16x8*)&sB[(s * 8 + 4 * wc + j) * 512 + le];
#pragma unroll
            for (int i = 0; i < 2; i++)
#pragma unroll
                for (int j = 0; j < 4; j++)
                    acc[i][j] = __builtin_amdgcn_mfma_f32_32x32x16_bf16(af[i], bfr[j], acc[i][j], 0, 0, 0);
        }
    }

    float g[16];
#pragma unroll
    for (int q = 0; q < 16; q++) g[q] = gm[q];

    const int Tn = N >> 4;
#pragma unroll
    for (int i = 0; i < 2; i++) {
        size_t RBo = (size_t)(row0 >> 5) + 2 * wr + i;
#pragma unroll
        for (int j = 0; j < 4; j++) {
            int c = col0 + (4 * wc + j) * 32 + m32;
            size_t tbase = (RBo * Tn + (c >> 4)) * 512;
            int coff = ((c >> 3) & 1) * 32;
            int cj = c & 7;
            float bsv = bias[c];
#pragma unroll
            for (int q = 0; q < 4; q++) {
#pragma unroll
                for (int n = 0; n < 4; n++) {
                    float v = g[n * 4 + 0] * acc[i][j][q * 4 + 0] +
                              g[n * 4 + 1] * acc[i][j][q * 4 + 1] +
                              g[n * 4 + 2] * acc[i][j][q * 4 + 2] +
                              g[n * 4 + 3] * acc[i][j][q * 4 + 3] + bsv;
                    out[tbase + (size_t)(coff + 4 * kh + 8 * q + n) * 8 + cj] =
                        (bf16)fmaxf(v, 0.f);
                }
            }
        }
    }
}

// ---------- SAGE GEMM: 128x256 tile, BK=64, R0-identical branch-free K-loop -
// NORM FUSION: insq = per-row ssq of the INPUT (nullptr => no scaling).
// Row-scaling commutes with GEMM; relu(h*inv)=inv*relu(h). Producer stores
// relu(tot) un-normalized (+ ssq of pre-relu tot); consumer scales acc quads
// by inv_in[row] before the node mix.
__global__ __launch_bounds__(256, 2) void gemm_sage(
    const bf16* __restrict__ A, int K,
    const bf16* __restrict__ Bt,
    const float* __restrict__ bias,
    bf16* __restrict__ out, int N,
    const float* __restrict__ gm, float* __restrict__ ssq,
    const float* __restrict__ insq) {
    __shared__ bf16 sA[8192];    // 16 slots (kslot s*4 + rowblk) x 512
    __shared__ bf16 sB[16384];   // 32 slots (kslot s*8 + colblk) x 512
    const int t = threadIdx.x;
    const int lane = t & 63;
    const int w = t >> 6;
    const int wr = w >> 1, wc = w & 1;
    const int lin = blockIdx.x + gridDim.x * blockIdx.y;
    const int C = gridDim.x;
    const int cls = lin & 7;
    const int s0 = lin >> 3;
    const int rpc = gridDim.y >> 3;
    const int sy = s0 / C;
    const int row0 = (cls * rpc + sy) * 128;
    const int col0 = (s0 - sy * C) * 256;
    const int m32 = lane & 31;
    const int kh = lane >> 5;

    f32x16 acc[2][4] = {};

    const int TK = K >> 4;
    const size_t tA  = ((size_t)(row0 >> 5) + w) * TK;
    const size_t tB0 = ((size_t)(col0 >> 5) + w) * TK;
    const size_t tB1 = ((size_t)(col0 >> 5) + w + 4) * TK;
    const int le = lane * 8;

    for (int kb = 0; kb < K; kb += 64) {
        int kt = kb >> 4;
#pragma unroll
        for (int s = 0; s < 4; s++) {
            glds16(A  + (tA  + kt + s) * 512 + le, &sA[(s * 4 + w) * 512]);
            glds16(Bt + (tB0 + kt + s) * 512 + le, &sB[(s * 8 + w) * 512]);
            glds16(Bt + (tB1 + kt + s) * 512 + le, &sB[(s * 8 + w + 4) * 512]);
        }
        __syncthreads();
#pragma unroll
        for (int s = 0; s < 4; s++) {
            bf16x8 af[2], bfr[4];
#pragma unroll
            for (int i = 0; i < 2; i++)
                af[i] = *(const bf16x8*)&sA[(s * 4 + 2 * wr + i) * 512 + le];
#pragma unroll
            for (int j = 0; j < 4; j++)
                bfr[j] = *(const bf16x8*)&sB[(s * 8 + 4 * wc + j) * 512 + le];
#pragma unroll
            for (int i = 0; i < 2; i++)
#pragma unroll
                for (int j = 0; j < 4; j++)
                    acc[i][j] = __builtin_amdgcn_mfma_f32_32x32x16_bf16(af[i], bfr[j], acc[i][j], 0, 0, 0);
        }
        __syncthreads();
    }

    float g[16];
#pragma unroll
    for (int q = 0; q < 16; q++) g[q] = gm[q];

    const int F = N >> 1;
    const int Tf = F >> 4;
    const bool ev = ((m32 & 1) == 0);
    const bool hasin = (insq != nullptr);
#pragma unroll
    for (int i = 0; i < 2; i++) {
        size_t RBo = (size_t)(row0 >> 5) + 2 * wr + i;
        int rbAbs = row0 + (2 * wr + i) * 32 + 4 * kh;
#pragma unroll
        for (int q = 0; q < 4; q++) {
            // fused input-norm: per-row inv of the producer's ssq
            float invq[4] = {1.f, 1.f, 1.f, 1.f};
            if (hasin) {
#pragma unroll
                for (int n = 0; n < 4; n++)
                    invq[n] = 1.f / fmaxf(sqrtf(insq[rbAbs + 8 * q + n]), 1e-12f);
            }
            float ssql[4] = {0.f, 0.f, 0.f, 0.f};
#pragma unroll
            for (int j = 0; j < 4; j++) {
                int c = col0 + (4 * wc + j) * 32 + m32;
                int f = c >> 1;
                size_t tbase = (RBo * Tf + (f >> 4)) * 512;
                int foff = ((f >> 3) & 1) * 32;
                int fj = f & 7;
                float bsv = bias[f];
                float a_s[4];
#pragma unroll
                for (int k2 = 0; k2 < 4; k2++)
                    a_s[k2] = acc[i][j][q * 4 + k2] * invq[k2];
                float mine[4];
                if (ev) {
#pragma unroll
                    for (int n = 0; n < 4; n++)
                        mine[n] = g[n * 4 + 0] * a_s[0] +
                                  g[n * 4 + 1] * a_s[1] +
                                  g[n * 4 + 2] * a_s[2] +
                                  g[n * 4 + 3] * a_s[3];
                } else {
#pragma unroll
                    for (int n = 0; n < 4; n++) mine[n] = a_s[n];
                }
#pragma unroll
                for (int n = 0; n < 4; n++) {
                    float oth = __shfl_xor(mine[n], 1);
                    float tot = mine[n] + oth + bsv;
                    ssql[n] += tot * tot;
                    if (ev)
                        out[tbase + (size_t)(foff + 4 * kh + 8 * q + n) * 8 + fj] =
                            (bf16)fmaxf(tot, 0.f);   // store relu'd un-normalized
                }
            }
#pragma unroll
            for (int n = 0; n < 4; n++) {
                float v = ssql[n];
                v += __shfl_xor(v, 1); v += __shfl_xor(v, 2);
                v += __shfl_xor(v, 4); v += __shfl_xor(v, 8);
                v += __shfl_xor(v, 16);
                ssql[n] = v;
            }
            if (m32 == 0) {
#pragma unroll
                for (int n = 0; n < 4; n++)
                    atomicAdd(&ssq[rbAbs + 8 * q + n], ssql[n] * 0.5f);
            }
        }
    }
}

// ---------- final FC (1024->10) + softmax, fused h4 norm+ReLU, FT input ----
// h4 FT[M,256] (T=16), stored relu'd un-normalized; relu(relu(t)*inv) =
// relu(t)*inv so the fused scaling stays exact.
// GRID-STRIDE (R11): fixed 512 blocks; each block stages the 40KB Wfc ONCE
// and loops elements (stride gridDim.x*4). Was: one element per wave ->
// 4096 blocks/slice x 40KB = 164MB redundant WT reads.
// Element e: rows 4e..4e+3 live in row-block e>>3 at m32 = 4*(e&7)+node.
// lane -> (ks=lane&15, node=lane>>4), jj loop = kh.
// FC feature index = node*256 + ks*16 + jj*8 + c  (node offset! R12 bug).
__global__ __launch_bounds__(256) void fc_softmax(const bf16x8* __restrict__ h,
                                                  const float* __restrict__ ssq4,
                                                  const float* __restrict__ Wfc,
                                                  const float* __restrict__ bfc,
                                                  float* __restrict__ outp,
                                                  int nE) {
    __shared__ float WT[10][1024];
    int t = threadIdx.x;
    for (int i = t; i < 10240; i += 256) { int o = i % 10, k = i / 10; WT[o][k] = Wfc[i]; }
    __syncthreads();
    int wid = t >> 6, lane = t & 63;
    int ks = lane & 15, node = lane >> 4;
    const size_t estep = (size_t)gridDim.x * 4;
    for (size_t e = (size_t)blockIdx.x * 4 + wid; e < (size_t)nE; e += estep) {
        size_t eb8 = e >> 3;
        int eo = (int)(e & 7);
        float inv = 1.f / fmaxf(sqrtf(ssq4[e * 4 + node]), 1e-12f);
        float acc[10];
#pragma unroll
        for (int o = 0; o < 10; o++) acc[o] = 0.f;
#pragma unroll
        for (int jj = 0; jj < 2; jj++) {
            size_t ch = (eb8 * 16 + ks) * 64 + jj * 32 + eo * 4 + node;
            bf16x8 v = h[ch];
            float f[8];
#pragma unroll
            for (int c = 0; c < 8; c++) f[c] = fmaxf((float)v[c] * inv, 0.f);
            int k0 = node * 256 + ks * 16 + jj * 8;
#pragma unroll
            for (int o = 0; o < 10; o++) {
                const float* wr = &WT[o][k0];
                float s = 0.f;
#pragma unroll
                for (int c = 0; c < 8; c++) s += f[c] * wr[c];
                acc[o] += s;
            }
        }
#pragma unroll
        for (int o = 0; o < 10; o++) {
            float v = acc[o];
            v += __shfl_xor(v, 32); v += __shfl_xor(v, 16); v += __shfl_xor(v, 8);
            v += __shfl_xor(v, 4);  v += __shfl_xor(v, 2);  v += __shfl_xor(v, 1);
            acc[o] = v + bfc[o];
        }
        float mx = acc[0];
#pragma unroll
        for (int o = 1; o < 10; o++) mx = fmaxf(mx, acc[o]);
        float sum = 0.f, p[10];
#pragma unroll
        for (int o = 0; o < 10; o++) { p[o] = expf(acc[o] - mx); sum += p[o]; }
        float inv2 = 1.f / sum;
        if (lane < 10) outp[e * 10 + lane] = p[lane] * inv2;
    }
}

// ---------------------------------------------------------------------------
extern "C" void kernel_launch(void* const* d_in, const int* in_sizes, int n_in,
                              void* d_out, int out_size, void* d_ws, size_t ws_size,
                              hipStream_t stream) {
    const float* x   = (const float*)d_in[0];
    const int*   ei  = (const int*)d_in[1];
    const float* W1  = (const float*)d_in[2];
    const float* b1  = (const float*)d_in[3];
    const float* Wl2 = (const float*)d_in[4];
    const float* bl2 = (const float*)d_in[5];
    const float* Wr2 = (const float*)d_in[6];
    const float* Wl3 = (const float*)d_in[7];
    const float* bl3 = (const float*)d_in[8];
    const float* Wr3 = (const float*)d_in[9];
    const float* Wl4 = (const float*)d_in[10];
    const float* bl4 = (const float*)d_in[11];
    const float* Wr4 = (const float*)d_in[12];
    const float* Wfc = (const float*)d_in[13];
    const float* bfc = (const float*)d_in[14];
    float* out = (float*)d_out;

    const int B = 32768;
    char* base = (char*)d_ws;
    float* gmat = (float*)base;
    bf16* Wt1 = (bf16*)(base + 4096);                  // FT [1024 x 64]
    bf16* Wt2 = Wt1 + 1024 * 64;                       // FT [1024 x 1024] interleaved
    bf16* Wt3 = Wt2 + 1024 * 1024;                     // FT [512 x 512]  interleaved
    bf16* Wt4 = Wt3 + 512 * 512;                       // FT [512 x 256]  interleaved
    float* ssqb = (float*)(Wt4 + 512 * 256);           // 12*B floats (all slices)
    char* sl  = (char*)(ssqb + 12 * B);
    size_t fixed = (size_t)(sl - base);

    // per-elem: R1 8192B + R2 4096B = 12288 B
    int Bs = B;
    while (Bs > 512 && fixed + (size_t)Bs * 12288 > ws_size) Bs >>= 1;
    int nslice = B / Bs;
    int M = Bs * 4;

    bf16* R1 = (bf16*)sl;                       // h1 FT [M,1024]; then h3 FT [M,256]
    bf16* R2 = R1 + (size_t)Bs * 4096;          // h2 FT [M,512]; then h4 FT [M,256]

    // one-shot prep: ssq zero + all weight transforms + edge setup
    hipLaunchKernelGGL(k_prep, dim3(6273), dim3(256), 0, stream,
                       ei, gmat, W1, Wl2, Wr2, Wl3, Wr3, Wl4, Wr4,
                       Wt1, Wt2, Wt3, Wt4, (float4*)ssqb);

    for (int s = 0; s < nslice; s++) {
        const float* xs = x + (size_t)s * Bs * 256;
        float* ssqs = ssqb + (size_t)s * 3 * M;       // disjoint per slice
        // L1 GCN: h1 = relu(mix(x@W1) + b1)  K=64; A = fp32 x (fused cast)
        hipLaunchKernelGGL(gemm_gcn, dim3(4, M / 128), dim3(256), 0, stream,
                           xs, Wt1, b1, R1, 1024, gmat);
        // L2 SAGE: relu(h2_un) (F=512) + ssq2   N=1024, K=1024
        hipLaunchKernelGGL(gemm_sage, dim3(4, M / 128), dim3(256), 0, stream,
                           R1, 1024, Wt2, bl2, R2, 1024, gmat + 16, ssqs,
                           (const float*)nullptr);
        // L3 SAGE: relu(h3_un) (F=256) into R1, input scaled by inv(ssq2)
        hipLaunchKernelGGL(gemm_sage, dim3(2, M / 128), dim3(256), 0, stream,
                           R2, 512, Wt3, bl3, R1, 512, gmat + 16, ssqs + M,
                           (const float*)ssqs);
        // L4 SAGE: relu(h4_un) (F=256) into R2, input scaled by inv(ssq3)
        hipLaunchKernelGGL(gemm_sage, dim3(2, M / 128), dim3(256), 0, stream,
                           R1, 256, Wt4, bl4, R2, 512, gmat + 16, ssqs + 2 * M,
                           (const float*)(ssqs + M));
        // FC + softmax with fused h4 norm (grid-stride, WT staged once/block)
        hipLaunchKernelGGL(fc_softmax, dim3(512), dim3(256), 0, stream,
                           (const bf16x8*)R2, ssqs + 2 * M, Wfc, bfc,
                           out + (size_t)s * Bs * 10, Bs);
    }
}

// Round 12
// 865.333 us; speedup vs baseline: 1.0719x; 1.0283x over previous
//
#include <hip/hip_runtime.h>
#include <stdint.h>
#include <math.h>

typedef __bf16 bf16;
typedef __attribute__((ext_vector_type(8))) __bf16 bf16x8;
typedef __attribute__((ext_vector_type(16))) float f32x16;

#define AS1 __attribute__((address_space(1)))
#define AS3 __attribute__((address_space(3)))

__device__ __forceinline__ void glds16(const void* g, void* l) {
    __builtin_amdgcn_global_load_lds((const AS1 uint32_t*)g, (AS3 uint32_t*)l, 16, 0, 0);
}

// Fragment-tile (FT) layout for X[M,K]: tile (rb=r>>5, ks=k>>4) is 512 elems:
// addr = (rb*(K/16)+ks)*512 + (((k>>3)&1)*32 + (r&31))*8 + (k&7).
// A wave's MFMA fragment = 1KB contiguous -> coalesced staging loads.
//
// SESSION LEDGER (gemm K-loop): R0 m97-2blk=187us/Mfma32 (ANCHOR); R1 8ph=194/31;
// R2 fat=206/28; R3 m201=227/26; R4 3blk=195/31+writeamp; R6 hybrid B-reg=204/29.
// K-loop CLOSED at ~31% MfmaUtil plateau. Fusion wins (all matched preds):
// R7 norm-fuse 945->913; R10 kernel-split restore 913; R11 fc grid-stride
// 913->890. R11 NOTE: profiled gemm=231us was a rocprof-pass artifact (timed
// total arithmetic proves gemm ~191 in production; trust graph-timed totals).
// R12: fc_softmax 512->1024 blocks (2x TLP, WT amortization still 4x).

// ---------- device helpers for weight transforms ---------------------------
__device__ __forceinline__ void wtransF_body(int a, const float* __restrict__ W,
                                             int K, int N, bf16* __restrict__ Wt) {
    int j = a & 7, c64 = (a >> 3) & 63, tile = a >> 9;
    int m32 = c64 & 31, kh = c64 >> 5;
    int TK = K >> 4;
    int rblk = tile / TK, ks = tile - rblk * TK;
    int n = rblk * 32 + m32, k = ks * 16 + kh * 8 + j;
    Wt[a] = (bf16)W[(size_t)k * N + n];
}

__device__ __forceinline__ void wtransI_body(int a, const float* __restrict__ Wl,
                                             const float* __restrict__ Wr,
                                             int K, int F, bf16* __restrict__ Bt) {
    int j = a & 7, c64 = (a >> 3) & 63, tile = a >> 9;
    int m32 = c64 & 31, kh = c64 >> 5;
    int TK = K >> 4;
    int rblk = tile / TK, ks = tile - rblk * TK;
    int n = rblk * 32 + m32, k = ks * 16 + kh * 8 + j;
    int f = n >> 1;
    float v = (n & 1) ? Wr[(size_t)k * F + f] : Wl[(size_t)k * F + f];
    Bt[a] = (bf16)v;
}

// ---------- one-shot prep: ssq zero + all weight transforms + edge setup ---
__global__ __launch_bounds__(256) void k_prep(
    const int* __restrict__ ei, float* __restrict__ gmat,
    const float* __restrict__ W1,
    const float* __restrict__ Wl2, const float* __restrict__ Wr2,
    const float* __restrict__ Wl3, const float* __restrict__ Wr3,
    const float* __restrict__ Wl4, const float* __restrict__ Wr4,
    bf16* __restrict__ Wt1, bf16* __restrict__ Wt2,
    bf16* __restrict__ Wt3, bf16* __restrict__ Wt4,
    float4* __restrict__ ssqz) {
    int b = blockIdx.x, t = threadIdx.x;
    if (b < 384) {
        int i = b * 256 + t;
        if (i < 3 * 32768) ssqz[i] = make_float4(0.f, 0.f, 0.f, 0.f);
        return;
    }
    b -= 384;
    if (b < 256) { wtransF_body(b * 256 + t, W1, 64, 1024, Wt1); return; }
    b -= 256;
    if (b < 4096) { wtransI_body(b * 256 + t, Wl2, Wr2, 1024, 512, Wt2); return; }
    b -= 4096;
    if (b < 1024) { wtransI_body(b * 256 + t, Wl3, Wr3, 512, 256, Wt3); return; }
    b -= 1024;
    if (b < 512) { wtransI_body(b * 256 + t, Wl4, Wr4, 256, 256, Wt4); return; }
    if (t != 0) return;
    // ---- edge setup: A_gcn (gmat[0..15]) and M_sage (gmat[16..31]) ----
    bool is64 = true;
    for (int i = 0; i < 12; i++) if (ei[2 * i + 1] != 0) { is64 = false; break; }
    int src[12], dst[12];
    for (int e = 0; e < 12; e++) {
        if (is64) { src[e] = ei[2 * e]; dst[e] = ei[24 + 2 * e]; }
        else      { src[e] = ei[e];     dst[e] = ei[12 + e]; }
    }
    float deg[4] = {1.f, 1.f, 1.f, 1.f};
    for (int e = 0; e < 12; e++) deg[dst[e]] += 1.f;
    float dinv[4];
    for (int n = 0; n < 4; n++) dinv[n] = 1.f / sqrtf(deg[n]);
    float A[16];
    for (int i = 0; i < 16; i++) A[i] = 0.f;
    for (int e = 0; e < 12; e++) A[dst[e] * 4 + src[e]] += dinv[src[e]] * dinv[dst[e]];
    for (int n = 0; n < 4; n++) A[n * 4 + n] += dinv[n] * dinv[n];
    float cnt[4] = {0.f, 0.f, 0.f, 0.f};
    for (int e = 0; e < 12; e++) cnt[dst[e]] += 1.f;
    for (int n = 0; n < 4; n++) cnt[n] = fmaxf(cnt[n], 1.f);
    float Mm[16];
    for (int i = 0; i < 16; i++) Mm[i] = 0.f;
    for (int e = 0; e < 12; e++) Mm[dst[e] * 4 + src[e]] += 1.f;
    for (int n = 0; n < 4; n++)
        for (int m = 0; m < 4; m++) Mm[n * 4 + m] /= cnt[n];
    for (int i = 0; i < 16; i++) { gmat[i] = A[i]; gmat[16 + i] = Mm[i]; }
}

// ---------- GCN GEMM (L1): K=64 single tile, fused fp32->bf16 staging ------
// A = raw fp32 x [M,64] (cast_x deleted); same FT slot layout as the staged
// path. Epilogue: node mix + bias + ReLU; write FT with next-K = N.
__global__ __launch_bounds__(256, 2) void gemm_gcn(
    const float* __restrict__ x,
    const bf16* __restrict__ Bt,
    const float* __restrict__ bias,
    bf16* __restrict__ out, int N,
    const float* __restrict__ gm) {
    __shared__ bf16 sA[8192];    // 16 slots (kslot s*4 + rowblk) x 512
    __shared__ bf16 sB[16384];   // 32 slots (kslot s*8 + colblk) x 512
    const int t = threadIdx.x;
    const int lane = t & 63;
    const int w = t >> 6;
    const int wr = w >> 1, wc = w & 1;
    const int lin = blockIdx.x + gridDim.x * blockIdx.y;
    const int C = gridDim.x;
    const int cls = lin & 7;
    const int s0 = lin >> 3;
    const int rpc = gridDim.y >> 3;
    const int sy = s0 / C;
    const int row0 = (cls * rpc + sy) * 128;
    const int col0 = (s0 - sy * C) * 256;
    const int m32 = lane & 31;
    const int kh = lane >> 5;

    f32x16 acc[2][4] = {};

    const int TK = 4;   // K=64
    const size_t tB0 = ((size_t)(col0 >> 5) + w) * TK;
    const size_t tB1 = ((size_t)(col0 >> 5) + w + 4) * TK;
    const int le = lane * 8;

    {
        const float4* xf = (const float4*)x;
        int r = row0 + w * 32 + m32;
#pragma unroll
        for (int s = 0; s < 4; s++) {
            float4 av = xf[(size_t)r * 16 + s * 4 + kh * 2];
            float4 bv = xf[(size_t)r * 16 + s * 4 + kh * 2 + 1];
            bf16x8 o;
            o[0] = (bf16)av.x; o[1] = (bf16)av.y;
            o[2] = (bf16)av.z; o[3] = (bf16)av.w;
            o[4] = (bf16)bv.x; o[5] = (bf16)bv.y;
            o[6] = (bf16)bv.z; o[7] = (bf16)bv.w;
            *(bf16x8*)&sA[(s * 4 + w) * 512 + le] = o;
        }
#pragma unroll
        for (int s = 0; s < 4; s++) {
            glds16(Bt + (tB0 + s) * 512 + le, &sB[(s * 8 + w) * 512]);
            glds16(Bt + (tB1 + s) * 512 + le, &sB[(s * 8 + w + 4) * 512]);
        }
        __syncthreads();
#pragma unroll
        for (int s = 0; s < 4; s++) {
            bf16x8 af[2], bfr[4];
#pragma unroll
            for (int i = 0; i < 2; i++)
                af[i] = *(const bf16x8*)&sA[(s * 4 + 2 * wr + i) * 512 + le];
#pragma unroll
            for (int j = 0; j < 4; j++)
                bfr[j] = *(const bf16x8*)&sB[(s * 8 + 4 * wc + j) * 512 + le];
#pragma unroll
            for (int i = 0; i < 2; i++)
#pragma unroll
                for (int j = 0; j < 4; j++)
                    acc[i][j] = __builtin_amdgcn_mfma_f32_32x32x16_bf16(af[i], bfr[j], acc[i][j], 0, 0, 0);
        }
    }

    float g[16];
#pragma unroll
    for (int q = 0; q < 16; q++) g[q] = gm[q];

    const int Tn = N >> 4;
#pragma unroll
    for (int i = 0; i < 2; i++) {
        size_t RBo = (size_t)(row0 >> 5) + 2 * wr + i;
#pragma unroll
        for (int j = 0; j < 4; j++) {
            int c = col0 + (4 * wc + j) * 32 + m32;
            size_t tbase = (RBo * Tn + (c >> 4)) * 512;
            int coff = ((c >> 3) & 1) * 32;
            int cj = c & 7;
            float bsv = bias[c];
#pragma unroll
            for (int q = 0; q < 4; q++) {
#pragma unroll
                for (int n = 0; n < 4; n++) {
                    float v = g[n * 4 + 0] * acc[i][j][q * 4 + 0] +
                              g[n * 4 + 1] * acc[i][j][q * 4 + 1] +
                              g[n * 4 + 2] * acc[i][j][q * 4 + 2] +
                              g[n * 4 + 3] * acc[i][j][q * 4 + 3] + bsv;
                    out[tbase + (size_t)(coff + 4 * kh + 8 * q + n) * 8 + cj] =
                        (bf16)fmaxf(v, 0.f);
                }
            }
        }
    }
}

// ---------- SAGE GEMM: 128x256 tile, BK=64, R0-identical branch-free K-loop -
// NORM FUSION: insq = per-row ssq of the INPUT (nullptr => no scaling).
// Row-scaling commutes with GEMM; relu(h*inv)=inv*relu(h). Producer stores
// relu(tot) un-normalized (+ ssq of pre-relu tot); consumer scales acc quads
// by inv_in[row] before the node mix.
__global__ __launch_bounds__(256, 2) void gemm_sage(
    const bf16* __restrict__ A, int K,
    const bf16* __restrict__ Bt,
    const float* __restrict__ bias,
    bf16* __restrict__ out, int N,
    const float* __restrict__ gm, float* __restrict__ ssq,
    const float* __restrict__ insq) {
    __shared__ bf16 sA[8192];    // 16 slots (kslot s*4 + rowblk) x 512
    __shared__ bf16 sB[16384];   // 32 slots (kslot s*8 + colblk) x 512
    const int t = threadIdx.x;
    const int lane = t & 63;
    const int w = t >> 6;
    const int wr = w >> 1, wc = w & 1;
    const int lin = blockIdx.x + gridDim.x * blockIdx.y;
    const int C = gridDim.x;
    const int cls = lin & 7;
    const int s0 = lin >> 3;
    const int rpc = gridDim.y >> 3;
    const int sy = s0 / C;
    const int row0 = (cls * rpc + sy) * 128;
    const int col0 = (s0 - sy * C) * 256;
    const int m32 = lane & 31;
    const int kh = lane >> 5;

    f32x16 acc[2][4] = {};

    const int TK = K >> 4;
    const size_t tA  = ((size_t)(row0 >> 5) + w) * TK;
    const size_t tB0 = ((size_t)(col0 >> 5) + w) * TK;
    const size_t tB1 = ((size_t)(col0 >> 5) + w + 4) * TK;
    const int le = lane * 8;

    for (int kb = 0; kb < K; kb += 64) {
        int kt = kb >> 4;
#pragma unroll
        for (int s = 0; s < 4; s++) {
            glds16(A  + (tA  + kt + s) * 512 + le, &sA[(s * 4 + w) * 512]);
            glds16(Bt + (tB0 + kt + s) * 512 + le, &sB[(s * 8 + w) * 512]);
            glds16(Bt + (tB1 + kt + s) * 512 + le, &sB[(s * 8 + w + 4) * 512]);
        }
        __syncthreads();
#pragma unroll
        for (int s = 0; s < 4; s++) {
            bf16x8 af[2], bfr[4];
#pragma unroll
            for (int i = 0; i < 2; i++)
                af[i] = *(const bf16x8*)&sA[(s * 4 + 2 * wr + i) * 512 + le];
#pragma unroll
            for (int j = 0; j < 4; j++)
                bfr[j] = *(const bf16x8*)&sB[(s * 8 + 4 * wc + j) * 512 + le];
#pragma unroll
            for (int i = 0; i < 2; i++)
#pragma unroll
                for (int j = 0; j < 4; j++)
                    acc[i][j] = __builtin_amdgcn_mfma_f32_32x32x16_bf16(af[i], bfr[j], acc[i][j], 0, 0, 0);
        }
        __syncthreads();
    }

    float g[16];
#pragma unroll
    for (int q = 0; q < 16; q++) g[q] = gm[q];

    const int F = N >> 1;
    const int Tf = F >> 4;
    const bool ev = ((m32 & 1) == 0);
    const bool hasin = (insq != nullptr);
#pragma unroll
    for (int i = 0; i < 2; i++) {
        size_t RBo = (size_t)(row0 >> 5) + 2 * wr + i;
        int rbAbs = row0 + (2 * wr + i) * 32 + 4 * kh;
#pragma unroll
        for (int q = 0; q < 4; q++) {
            // fused input-norm: per-row inv of the producer's ssq
            float invq[4] = {1.f, 1.f, 1.f, 1.f};
            if (hasin) {
#pragma unroll
                for (int n = 0; n < 4; n++)
                    invq[n] = 1.f / fmaxf(sqrtf(insq[rbAbs + 8 * q + n]), 1e-12f);
            }
            float ssql[4] = {0.f, 0.f, 0.f, 0.f};
#pragma unroll
            for (int j = 0; j < 4; j++) {
                int c = col0 + (4 * wc + j) * 32 + m32;
                int f = c >> 1;
                size_t tbase = (RBo * Tf + (f >> 4)) * 512;
                int foff = ((f >> 3) & 1) * 32;
                int fj = f & 7;
                float bsv = bias[f];
                float a_s[4];
#pragma unroll
                for (int k2 = 0; k2 < 4; k2++)
                    a_s[k2] = acc[i][j][q * 4 + k2] * invq[k2];
                float mine[4];
                if (ev) {
#pragma unroll
                    for (int n = 0; n < 4; n++)
                        mine[n] = g[n * 4 + 0] * a_s[0] +
                                  g[n * 4 + 1] * a_s[1] +
                                  g[n * 4 + 2] * a_s[2] +
                                  g[n * 4 + 3] * a_s[3];
                } else {
#pragma unroll
                    for (int n = 0; n < 4; n++) mine[n] = a_s[n];
                }
#pragma unroll
                for (int n = 0; n < 4; n++) {
                    float oth = __shfl_xor(mine[n], 1);
                    float tot = mine[n] + oth + bsv;
                    ssql[n] += tot * tot;
                    if (ev)
                        out[tbase + (size_t)(foff + 4 * kh + 8 * q + n) * 8 + fj] =
                            (bf16)fmaxf(tot, 0.f);   // store relu'd un-normalized
                }
            }
#pragma unroll
            for (int n = 0; n < 4; n++) {
                float v = ssql[n];
                v += __shfl_xor(v, 1); v += __shfl_xor(v, 2);
                v += __shfl_xor(v, 4); v += __shfl_xor(v, 8);
                v += __shfl_xor(v, 16);
                ssql[n] = v;
            }
            if (m32 == 0) {
#pragma unroll
                for (int n = 0; n < 4; n++)
                    atomicAdd(&ssq[rbAbs + 8 * q + n], ssql[n] * 0.5f);
            }
        }
    }
}

// ---------- final FC (1024->10) + softmax, fused h4 norm+ReLU, FT input ----
// h4 FT[M,256] (T=16), stored relu'd un-normalized; relu(relu(t)*inv) =
// relu(t)*inv so the fused scaling stays exact.
// GRID-STRIDE: 1024 blocks (R12: was 512 -- 2x TLP for the latency-bound h4
// stream; WT staging 41MB/slice, still 4x less than the original 164MB).
// Element e: rows 4e..4e+3 live in row-block e>>3 at m32 = 4*(e&7)+node.
// lane -> (ks=lane&15, node=lane>>4), jj loop = kh.
// FC feature index = node*256 + ks*16 + jj*8 + c  (node offset! R12 bug).
__global__ __launch_bounds__(256) void fc_softmax(const bf16x8* __restrict__ h,
                                                  const float* __restrict__ ssq4,
                                                  const float* __restrict__ Wfc,
                                                  const float* __restrict__ bfc,
                                                  float* __restrict__ outp,
                                                  int nE) {
    __shared__ float WT[10][1024];
    int t = threadIdx.x;
    for (int i = t; i < 10240; i += 256) { int o = i % 10, k = i / 10; WT[o][k] = Wfc[i]; }
    __syncthreads();
    int wid = t >> 6, lane = t & 63;
    int ks = lane & 15, node = lane >> 4;
    const size_t estep = (size_t)gridDim.x * 4;
    for (size_t e = (size_t)blockIdx.x * 4 + wid; e < (size_t)nE; e += estep) {
        size_t eb8 = e >> 3;
        int eo = (int)(e & 7);
        float inv = 1.f / fmaxf(sqrtf(ssq4[e * 4 + node]), 1e-12f);
        float acc[10];
#pragma unroll
        for (int o = 0; o < 10; o++) acc[o] = 0.f;
#pragma unroll
        for (int jj = 0; jj < 2; jj++) {
            size_t ch = (eb8 * 16 + ks) * 64 + jj * 32 + eo * 4 + node;
            bf16x8 v = h[ch];
            float f[8];
#pragma unroll
            for (int c = 0; c < 8; c++) f[c] = fmaxf((float)v[c] * inv, 0.f);
            int k0 = node * 256 + ks * 16 + jj * 8;
#pragma unroll
            for (int o = 0; o < 10; o++) {
                const float* wr = &WT[o][k0];
                float s = 0.f;
#pragma unroll
                for (int c = 0; c < 8; c++) s += f[c] * wr[c];
                acc[o] += s;
            }
        }
#pragma unroll
        for (int o = 0; o < 10; o++) {
            float v = acc[o];
            v += __shfl_xor(v, 32); v += __shfl_xor(v, 16); v += __shfl_xor(v, 8);
            v += __shfl_xor(v, 4);  v += __shfl_xor(v, 2);  v += __shfl_xor(v, 1);
            acc[o] = v + bfc[o];
        }
        float mx = acc[0];
#pragma unroll
        for (int o = 1; o < 10; o++) mx = fmaxf(mx, acc[o]);
        float sum = 0.f, p[10];
#pragma unroll
        for (int o = 0; o < 10; o++) { p[o] = expf(acc[o] - mx); sum += p[o]; }
        float inv2 = 1.f / sum;
        if (lane < 10) outp[e * 10 + lane] = p[lane] * inv2;
    }
}

// ---------------------------------------------------------------------------
extern "C" void kernel_launch(void* const* d_in, const int* in_sizes, int n_in,
                              void* d_out, int out_size, void* d_ws, size_t ws_size,
                              hipStream_t stream) {
    const float* x   = (const float*)d_in[0];
    const int*   ei  = (const int*)d_in[1];
    const float* W1  = (const float*)d_in[2];
    const float* b1  = (const float*)d_in[3];
    const float* Wl2 = (const float*)d_in[4];
    const float* bl2 = (const float*)d_in[5];
    const float* Wr2 = (const float*)d_in[6];
    const float* Wl3 = (const float*)d_in[7];
    const float* bl3 = (const float*)d_in[8];
    const float* Wr3 = (const float*)d_in[9];
    const float* Wl4 = (const float*)d_in[10];
    const float* bl4 = (const float*)d_in[11];
    const float* Wr4 = (const float*)d_in[12];
    const float* Wfc = (const float*)d_in[13];
    const float* bfc = (const float*)d_in[14];
    float* out = (float*)d_out;

    const int B = 32768;
    char* base = (char*)d_ws;
    float* gmat = (float*)base;
    bf16* Wt1 = (bf16*)(base + 4096);                  // FT [1024 x 64]
    bf16* Wt2 = Wt1 + 1024 * 64;                       // FT [1024 x 1024] interleaved
    bf16* Wt3 = Wt2 + 1024 * 1024;                     // FT [512 x 512]  interleaved
    bf16* Wt4 = Wt3 + 512 * 512;                       // FT [512 x 256]  interleaved
    float* ssqb = (float*)(Wt4 + 512 * 256);           // 12*B floats (all slices)
    char* sl  = (char*)(ssqb + 12 * B);
    size_t fixed = (size_t)(sl - base);

    // per-elem: R1 8192B + R2 4096B = 12288 B
    int Bs = B;
    while (Bs > 512 && fixed + (size_t)Bs * 12288 > ws_size) Bs >>= 1;
    int nslice = B / Bs;
    int M = Bs * 4;

    bf16* R1 = (bf16*)sl;                       // h1 FT [M,1024]; then h3 FT [M,256]
    bf16* R2 = R1 + (size_t)Bs * 4096;          // h2 FT [M,512]; then h4 FT [M,256]

    // one-shot prep: ssq zero + all weight transforms + edge setup
    hipLaunchKernelGGL(k_prep, dim3(6273), dim3(256), 0, stream,
                       ei, gmat, W1, Wl2, Wr2, Wl3, Wr3, Wl4, Wr4,
                       Wt1, Wt2, Wt3, Wt4, (float4*)ssqb);

    for (int s = 0; s < nslice; s++) {
        const float* xs = x + (size_t)s * Bs * 256;
        float* ssqs = ssqb + (size_t)s * 3 * M;       // disjoint per slice
        // L1 GCN: h1 = relu(mix(x@W1) + b1)  K=64; A = fp32 x (fused cast)
        hipLaunchKernelGGL(gemm_gcn, dim3(4, M / 128), dim3(256), 0, stream,
                           xs, Wt1, b1, R1, 1024, gmat);
        // L2 SAGE: relu(h2_un) (F=512) + ssq2   N=1024, K=1024
        hipLaunchKernelGGL(gemm_sage, dim3(4, M / 128), dim3(256), 0, stream,
                           R1, 1024, Wt2, bl2, R2, 1024, gmat + 16, ssqs,
                           (const float*)nullptr);
        // L3 SAGE: relu(h3_un) (F=256) into R1, input scaled by inv(ssq2)
        hipLaunchKernelGGL(gemm_sage, dim3(2, M / 128), dim3(256), 0, stream,
                           R2, 512, Wt3, bl3, R1, 512, gmat + 16, ssqs + M,
                           (const float*)ssqs);
        // L4 SAGE: relu(h4_un) (F=256) into R2, input scaled by inv(ssq3)
        hipLaunchKernelGGL(gemm_sage, dim3(2, M / 128), dim3(256), 0, stream,
                           R1, 256, Wt4, bl4, R2, 512, gmat + 16, ssqs + 2 * M,
                           (const float*)(ssqs + M));
        // FC + softmax with fused h4 norm (grid-stride, WT staged once/block)
        hipLaunchKernelGGL(fc_softmax, dim3(1024), dim3(256), 0, stream,
                           (const bf16x8*)R2, ssqs + 2 * M, Wfc, bfc,
                           out + (size_t)s * Bs * 10, Bs);
    }
}

// Round 13
// 852.834 us; speedup vs baseline: 1.0877x; 1.0147x over previous
//
#include <hip/hip_runtime.h>
#include <stdint.h>
#include <math.h>

typedef __bf16 bf16;
typedef __attribute__((ext_vector_type(8))) __bf16 bf16x8;
typedef __attribute__((ext_vector_type(16))) float f32x16;

#define AS1 __attribute__((address_space(1)))
#define AS3 __attribute__((address_space(3)))

__device__ __forceinline__ void glds16(const void* g, void* l) {
    __builtin_amdgcn_global_load_lds((const AS1 uint32_t*)g, (AS3 uint32_t*)l, 16, 0, 0);
}

// Fragment-tile (FT) layout for X[M,K]: tile (rb=r>>5, ks=k>>4) is 512 elems:
// addr = (rb*(K/16)+ks)*512 + (((k>>3)&1)*32 + (r&31))*8 + (k&7).
// A wave's MFMA fragment = 1KB contiguous -> coalesced staging loads.
//
// SESSION LEDGER (gemm K-loop): R0 m97-2blk=187us/Mfma32 (ANCHOR); R1 8ph=194/31;
// R2 fat=206/28; R3 m201=227/26; R4 3blk=195/31+writeamp; R6 hybrid B-reg=204/29.
// K-loop CLOSED at ~31% MfmaUtil plateau. Fusion wins (matched preds):
// R7 norm-fuse 945->913; R10 split restore 913; R11 fc grid-stride 913->890;
// R12 fc 1024 blocks 890->865 (fc TLP was the live lever -- fc was ~45us!).
// Profile NOTE: R11/R12 each had one absurd gemm_sage row (231us/20.7ms) --
// rocprof replay artifacts; production totals arithmetic excludes them.
// R13: fc 512-thread blocks -> 4 blk/CU x 8 waves = 32 waves/CU (HW max),
// fp32 WT kept (zero numerics change).

// ---------- device helpers for weight transforms ---------------------------
__device__ __forceinline__ void wtransF_body(int a, const float* __restrict__ W,
                                             int K, int N, bf16* __restrict__ Wt) {
    int j = a & 7, c64 = (a >> 3) & 63, tile = a >> 9;
    int m32 = c64 & 31, kh = c64 >> 5;
    int TK = K >> 4;
    int rblk = tile / TK, ks = tile - rblk * TK;
    int n = rblk * 32 + m32, k = ks * 16 + kh * 8 + j;
    Wt[a] = (bf16)W[(size_t)k * N + n];
}

__device__ __forceinline__ void wtransI_body(int a, const float* __restrict__ Wl,
                                             const float* __restrict__ Wr,
                                             int K, int F, bf16* __restrict__ Bt) {
    int j = a & 7, c64 = (a >> 3) & 63, tile = a >> 9;
    int m32 = c64 & 31, kh = c64 >> 5;
    int TK = K >> 4;
    int rblk = tile / TK, ks = tile - rblk * TK;
    int n = rblk * 32 + m32, k = ks * 16 + kh * 8 + j;
    int f = n >> 1;
    float v = (n & 1) ? Wr[(size_t)k * F + f] : Wl[(size_t)k * F + f];
    Bt[a] = (bf16)v;
}

// ---------- one-shot prep: ssq zero + all weight transforms + edge setup ---
__global__ __launch_bounds__(256) void k_prep(
    const int* __restrict__ ei, float* __restrict__ gmat,
    const float* __restrict__ W1,
    const float* __restrict__ Wl2, const float* __restrict__ Wr2,
    const float* __restrict__ Wl3, const float* __restrict__ Wr3,
    const float* __restrict__ Wl4, const float* __restrict__ Wr4,
    bf16* __restrict__ Wt1, bf16* __restrict__ Wt2,
    bf16* __restrict__ Wt3, bf16* __restrict__ Wt4,
    float4* __restrict__ ssqz) {
    int b = blockIdx.x, t = threadIdx.x;
    if (b < 384) {
        int i = b * 256 + t;
        if (i < 3 * 32768) ssqz[i] = make_float4(0.f, 0.f, 0.f, 0.f);
        return;
    }
    b -= 384;
    if (b < 256) { wtransF_body(b * 256 + t, W1, 64, 1024, Wt1); return; }
    b -= 256;
    if (b < 4096) { wtransI_body(b * 256 + t, Wl2, Wr2, 1024, 512, Wt2); return; }
    b -= 4096;
    if (b < 1024) { wtransI_body(b * 256 + t, Wl3, Wr3, 512, 256, Wt3); return; }
    b -= 1024;
    if (b < 512) { wtransI_body(b * 256 + t, Wl4, Wr4, 256, 256, Wt4); return; }
    if (t != 0) return;
    // ---- edge setup: A_gcn (gmat[0..15]) and M_sage (gmat[16..31]) ----
    bool is64 = true;
    for (int i = 0; i < 12; i++) if (ei[2 * i + 1] != 0) { is64 = false; break; }
    int src[12], dst[12];
    for (int e = 0; e < 12; e++) {
        if (is64) { src[e] = ei[2 * e]; dst[e] = ei[24 + 2 * e]; }
        else      { src[e] = ei[e];     dst[e] = ei[12 + e]; }
    }
    float deg[4] = {1.f, 1.f, 1.f, 1.f};
    for (int e = 0; e < 12; e++) deg[dst[e]] += 1.f;
    float dinv[4];
    for (int n = 0; n < 4; n++) dinv[n] = 1.f / sqrtf(deg[n]);
    float A[16];
    for (int i = 0; i < 16; i++) A[i] = 0.f;
    for (int e = 0; e < 12; e++) A[dst[e] * 4 + src[e]] += dinv[src[e]] * dinv[dst[e]];
    for (int n = 0; n < 4; n++) A[n * 4 + n] += dinv[n] * dinv[n];
    float cnt[4] = {0.f, 0.f, 0.f, 0.f};
    for (int e = 0; e < 12; e++) cnt[dst[e]] += 1.f;
    for (int n = 0; n < 4; n++) cnt[n] = fmaxf(cnt[n], 1.f);
    float Mm[16];
    for (int i = 0; i < 16; i++) Mm[i] = 0.f;
    for (int e = 0; e < 12; e++) Mm[dst[e] * 4 + src[e]] += 1.f;
    for (int n = 0; n < 4; n++)
        for (int m = 0; m < 4; m++) Mm[n * 4 + m] /= cnt[n];
    for (int i = 0; i < 16; i++) { gmat[i] = A[i]; gmat[16 + i] = Mm[i]; }
}

// ---------- GCN GEMM (L1): K=64 single tile, fused fp32->bf16 staging ------
// A = raw fp32 x [M,64] (cast_x deleted); same FT slot layout as the staged
// path. Epilogue: node mix + bias + ReLU; write FT with next-K = N.
__global__ __launch_bounds__(256, 2) void gemm_gcn(
    const float* __restrict__ x,
    const bf16* __restrict__ Bt,
    const float* __restrict__ bias,
    bf16* __restrict__ out, int N,
    const float* __restrict__ gm) {
    __shared__ bf16 sA[8192];    // 16 slots (kslot s*4 + rowblk) x 512
    __shared__ bf16 sB[16384];   // 32 slots (kslot s*8 + colblk) x 512
    const int t = threadIdx.x;
    const int lane = t & 63;
    const int w = t >> 6;
    const int wr = w >> 1, wc = w & 1;
    const int lin = blockIdx.x + gridDim.x * blockIdx.y;
    const int C = gridDim.x;
    const int cls = lin & 7;
    const int s0 = lin >> 3;
    const int rpc = gridDim.y >> 3;
    const int sy = s0 / C;
    const int row0 = (cls * rpc + sy) * 128;
    const int col0 = (s0 - sy * C) * 256;
    const int m32 = lane & 31;
    const int kh = lane >> 5;

    f32x16 acc[2][4] = {};

    const int TK = 4;   // K=64
    const size_t tB0 = ((size_t)(col0 >> 5) + w) * TK;
    const size_t tB1 = ((size_t)(col0 >> 5) + w + 4) * TK;
    const int le = lane * 8;

    {
        const float4* xf = (const float4*)x;
        int r = row0 + w * 32 + m32;
#pragma unroll
        for (int s = 0; s < 4; s++) {
            float4 av = xf[(size_t)r * 16 + s * 4 + kh * 2];
            float4 bv = xf[(size_t)r * 16 + s * 4 + kh * 2 + 1];
            bf16x8 o;
            o[0] = (bf16)av.x; o[1] = (bf16)av.y;
            o[2] = (bf16)av.z; o[3] = (bf16)av.w;
            o[4] = (bf16)bv.x; o[5] = (bf16)bv.y;
            o[6] = (bf16)bv.z; o[7] = (bf16)bv.w;
            *(bf16x8*)&sA[(s * 4 + w) * 512 + le] = o;
        }
#pragma unroll
        for (int s = 0; s < 4; s++) {
            glds16(Bt + (tB0 + s) * 512 + le, &sB[(s * 8 + w) * 512]);
            glds16(Bt + (tB1 + s) * 512 + le, &sB[(s * 8 + w + 4) * 512]);
        }
        __syncthreads();
#pragma unroll
        for (int s = 0; s < 4; s++) {
            bf16x8 af[2], bfr[4];
#pragma unroll
            for (int i = 0; i < 2; i++)
                af[i] = *(const bf16x8*)&sA[(s * 4 + 2 * wr + i) * 512 + le];
#pragma unroll
            for (int j = 0; j < 4; j++)
                bfr[j] = *(const bf16x8*)&sB[(s * 8 + 4 * wc + j) * 512 + le];
#pragma unroll
            for (int i = 0; i < 2; i++)
#pragma unroll
                for (int j = 0; j < 4; j++)
                    acc[i][j] = __builtin_amdgcn_mfma_f32_32x32x16_bf16(af[i], bfr[j], acc[i][j], 0, 0, 0);
        }
    }

    float g[16];
#pragma unroll
    for (int q = 0; q < 16; q++) g[q] = gm[q];

    const int Tn = N >> 4;
#pragma unroll
    for (int i = 0; i < 2; i++) {
        size_t RBo = (size_t)(row0 >> 5) + 2 * wr + i;
#pragma unroll
        for (int j = 0; j < 4; j++) {
            int c = col0 + (4 * wc + j) * 32 + m32;
            size_t tbase = (RBo * Tn + (c >> 4)) * 512;
            int coff = ((c >> 3) & 1) * 32;
            int cj = c & 7;
            float bsv = bias[c];
#pragma unroll
            for (int q = 0; q < 4; q++) {
#pragma unroll
                for (int n = 0; n < 4; n++) {
                    float v = g[n * 4 + 0] * acc[i][j][q * 4 + 0] +
                              g[n * 4 + 1] * acc[i][j][q * 4 + 1] +
                              g[n * 4 + 2] * acc[i][j][q * 4 + 2] +
                              g[n * 4 + 3] * acc[i][j][q * 4 + 3] + bsv;
                    out[tbase + (size_t)(coff + 4 * kh + 8 * q + n) * 8 + cj] =
                        (bf16)fmaxf(v, 0.f);
                }
            }
        }
    }
}

// ---------- SAGE GEMM: 128x256 tile, BK=64, R0-identical branch-free K-loop -
// NORM FUSION: insq = per-row ssq of the INPUT (nullptr => no scaling).
// Row-scaling commutes with GEMM; relu(h*inv)=inv*relu(h). Producer stores
// relu(tot) un-normalized (+ ssq of pre-relu tot); consumer scales acc quads
// by inv_in[row] before the node mix.
__global__ __launch_bounds__(256, 2) void gemm_sage(
    const bf16* __restrict__ A, int K,
    const bf16* __restrict__ Bt,
    const float* __restrict__ bias,
    bf16* __restrict__ out, int N,
    const float* __restrict__ gm, float* __restrict__ ssq,
    const float* __restrict__ insq) {
    __shared__ bf16 sA[8192];    // 16 slots (kslot s*4 + rowblk) x 512
    __shared__ bf16 sB[16384];   // 32 slots (kslot s*8 + colblk) x 512
    const int t = threadIdx.x;
    const int lane = t & 63;
    const int w = t >> 6;
    const int wr = w >> 1, wc = w & 1;
    const int lin = blockIdx.x + gridDim.x * blockIdx.y;
    const int C = gridDim.x;
    const int cls = lin & 7;
    const int s0 = lin >> 3;
    const int rpc = gridDim.y >> 3;
    const int sy = s0 / C;
    const int row0 = (cls * rpc + sy) * 128;
    const int col0 = (s0 - sy * C) * 256;
    const int m32 = lane & 31;
    const int kh = lane >> 5;

    f32x16 acc[2][4] = {};

    const int TK = K >> 4;
    const size_t tA  = ((size_t)(row0 >> 5) + w) * TK;
    const size_t tB0 = ((size_t)(col0 >> 5) + w) * TK;
    const size_t tB1 = ((size_t)(col0 >> 5) + w + 4) * TK;
    const int le = lane * 8;

    for (int kb = 0; kb < K; kb += 64) {
        int kt = kb >> 4;
#pragma unroll
        for (int s = 0; s < 4; s++) {
            glds16(A  + (tA  + kt + s) * 512 + le, &sA[(s * 4 + w) * 512]);
            glds16(Bt + (tB0 + kt + s) * 512 + le, &sB[(s * 8 + w) * 512]);
            glds16(Bt + (tB1 + kt + s) * 512 + le, &sB[(s * 8 + w + 4) * 512]);
        }
        __syncthreads();
#pragma unroll
        for (int s = 0; s < 4; s++) {
            bf16x8 af[2], bfr[4];
#pragma unroll
            for (int i = 0; i < 2; i++)
                af[i] = *(const bf16x8*)&sA[(s * 4 + 2 * wr + i) * 512 + le];
#pragma unroll
            for (int j = 0; j < 4; j++)
                bfr[j] = *(const bf16x8*)&sB[(s * 8 + 4 * wc + j) * 512 + le];
#pragma unroll
            for (int i = 0; i < 2; i++)
#pragma unroll
                for (int j = 0; j < 4; j++)
                    acc[i][j] = __builtin_amdgcn_mfma_f32_32x32x16_bf16(af[i], bfr[j], acc[i][j], 0, 0, 0);
        }
        __syncthreads();
    }

    float g[16];
#pragma unroll
    for (int q = 0; q < 16; q++) g[q] = gm[q];

    const int F = N >> 1;
    const int Tf = F >> 4;
    const bool ev = ((m32 & 1) == 0);
    const bool hasin = (insq != nullptr);
#pragma unroll
    for (int i = 0; i < 2; i++) {
        size_t RBo = (size_t)(row0 >> 5) + 2 * wr + i;
        int rbAbs = row0 + (2 * wr + i) * 32 + 4 * kh;
#pragma unroll
        for (int q = 0; q < 4; q++) {
            // fused input-norm: per-row inv of the producer's ssq
            float invq[4] = {1.f, 1.f, 1.f, 1.f};
            if (hasin) {
#pragma unroll
                for (int n = 0; n < 4; n++)
                    invq[n] = 1.f / fmaxf(sqrtf(insq[rbAbs + 8 * q + n]), 1e-12f);
            }
            float ssql[4] = {0.f, 0.f, 0.f, 0.f};
#pragma unroll
            for (int j = 0; j < 4; j++) {
                int c = col0 + (4 * wc + j) * 32 + m32;
                int f = c >> 1;
                size_t tbase = (RBo * Tf + (f >> 4)) * 512;
                int foff = ((f >> 3) & 1) * 32;
                int fj = f & 7;
                float bsv = bias[f];
                float a_s[4];
#pragma unroll
                for (int k2 = 0; k2 < 4; k2++)
                    a_s[k2] = acc[i][j][q * 4 + k2] * invq[k2];
                float mine[4];
                if (ev) {
#pragma unroll
                    for (int n = 0; n < 4; n++)
                        mine[n] = g[n * 4 + 0] * a_s[0] +
                                  g[n * 4 + 1] * a_s[1] +
                                  g[n * 4 + 2] * a_s[2] +
                                  g[n * 4 + 3] * a_s[3];
                } else {
#pragma unroll
                    for (int n = 0; n < 4; n++) mine[n] = a_s[n];
                }
#pragma unroll
                for (int n = 0; n < 4; n++) {
                    float oth = __shfl_xor(mine[n], 1);
                    float tot = mine[n] + oth + bsv;
                    ssql[n] += tot * tot;
                    if (ev)
                        out[tbase + (size_t)(foff + 4 * kh + 8 * q + n) * 8 + fj] =
                            (bf16)fmaxf(tot, 0.f);   // store relu'd un-normalized
                }
            }
#pragma unroll
            for (int n = 0; n < 4; n++) {
                float v = ssql[n];
                v += __shfl_xor(v, 1); v += __shfl_xor(v, 2);
                v += __shfl_xor(v, 4); v += __shfl_xor(v, 8);
                v += __shfl_xor(v, 16);
                ssql[n] = v;
            }
            if (m32 == 0) {
#pragma unroll
                for (int n = 0; n < 4; n++)
                    atomicAdd(&ssq[rbAbs + 8 * q + n], ssql[n] * 0.5f);
            }
        }
    }
}

// ---------- final FC (1024->10) + softmax, fused h4 norm+ReLU, FT input ----
// h4 FT[M,256] (T=16), stored relu'd un-normalized; relu(relu(t)*inv) =
// relu(t)*inv so the fused scaling stays exact.
// R13: 512-THREAD blocks (8 waves) -- LDS 40KB => 4 blocks/CU x 8 waves =
// 32 waves/CU (HW max), double R12's TLP; fp32 WT unchanged (zero numerics
// delta). Grid-stride over elements; WT staged once per block.
// Element e: rows 4e..4e+3 live in row-block e>>3 at m32 = 4*(e&7)+node.
// lane -> (ks=lane&15, node=lane>>4), jj loop = kh.
// FC feature index = node*256 + ks*16 + jj*8 + c  (node offset! R12 bug).
__global__ __launch_bounds__(512) void fc_softmax(const bf16x8* __restrict__ h,
                                                  const float* __restrict__ ssq4,
                                                  const float* __restrict__ Wfc,
                                                  const float* __restrict__ bfc,
                                                  float* __restrict__ outp,
                                                  int nE) {
    __shared__ float WT[10][1024];
    int t = threadIdx.x;
    for (int i = t; i < 10240; i += 512) { int o = i % 10, k = i / 10; WT[o][k] = Wfc[i]; }
    __syncthreads();
    int wid = t >> 6, lane = t & 63;    // 8 waves per block
    int ks = lane & 15, node = lane >> 4;
    const size_t estep = (size_t)gridDim.x * 8;
    for (size_t e = (size_t)blockIdx.x * 8 + wid; e < (size_t)nE; e += estep) {
        size_t eb8 = e >> 3;
        int eo = (int)(e & 7);
        float inv = 1.f / fmaxf(sqrtf(ssq4[e * 4 + node]), 1e-12f);
        float acc[10];
#pragma unroll
        for (int o = 0; o < 10; o++) acc[o] = 0.f;
#pragma unroll
        for (int jj = 0; jj < 2; jj++) {
            size_t ch = (eb8 * 16 + ks) * 64 + jj * 32 + eo * 4 + node;
            bf16x8 v = h[ch];
            float f[8];
#pragma unroll
            for (int c = 0; c < 8; c++) f[c] = fmaxf((float)v[c] * inv, 0.f);
            int k0 = node * 256 + ks * 16 + jj * 8;
#pragma unroll
            for (int o = 0; o < 10; o++) {
                const float* wr = &WT[o][k0];
                float s = 0.f;
#pragma unroll
                for (int c = 0; c < 8; c++) s += f[c] * wr[c];
                acc[o] += s;
            }
        }
#pragma unroll
        for (int o = 0; o < 10; o++) {
            float v = acc[o];
            v += __shfl_xor(v, 32); v += __shfl_xor(v, 16); v += __shfl_xor(v, 8);
            v += __shfl_xor(v, 4);  v += __shfl_xor(v, 2);  v += __shfl_xor(v, 1);
            acc[o] = v + bfc[o];
        }
        float mx = acc[0];
#pragma unroll
        for (int o = 1; o < 10; o++) mx = fmaxf(mx, acc[o]);
        float sum = 0.f, p[10];
#pragma unroll
        for (int o = 0; o < 10; o++) { p[o] = expf(acc[o] - mx); sum += p[o]; }
        float inv2 = 1.f / sum;
        if (lane < 10) outp[e * 10 + lane] = p[lane] * inv2;
    }
}

// ---------------------------------------------------------------------------
extern "C" void kernel_launch(void* const* d_in, const int* in_sizes, int n_in,
                              void* d_out, int out_size, void* d_ws, size_t ws_size,
                              hipStream_t stream) {
    const float* x   = (const float*)d_in[0];
    const int*   ei  = (const int*)d_in[1];
    const float* W1  = (const float*)d_in[2];
    const float* b1  = (const float*)d_in[3];
    const float* Wl2 = (const float*)d_in[4];
    const float* bl2 = (const float*)d_in[5];
    const float* Wr2 = (const float*)d_in[6];
    const float* Wl3 = (const float*)d_in[7];
    const float* bl3 = (const float*)d_in[8];
    const float* Wr3 = (const float*)d_in[9];
    const float* Wl4 = (const float*)d_in[10];
    const float* bl4 = (const float*)d_in[11];
    const float* Wr4 = (const float*)d_in[12];
    const float* Wfc = (const float*)d_in[13];
    const float* bfc = (const float*)d_in[14];
    float* out = (float*)d_out;

    const int B = 32768;
    char* base = (char*)d_ws;
    float* gmat = (float*)base;
    bf16* Wt1 = (bf16*)(base + 4096);                  // FT [1024 x 64]
    bf16* Wt2 = Wt1 + 1024 * 64;                       // FT [1024 x 1024] interleaved
    bf16* Wt3 = Wt2 + 1024 * 1024;                     // FT [512 x 512]  interleaved
    bf16* Wt4 = Wt3 + 512 * 512;                       // FT [512 x 256]  interleaved
    float* ssqb = (float*)(Wt4 + 512 * 256);           // 12*B floats (all slices)
    char* sl  = (char*)(ssqb + 12 * B);
    size_t fixed = (size_t)(sl - base);

    // per-elem: R1 8192B + R2 4096B = 12288 B
    int Bs = B;
    while (Bs > 512 && fixed + (size_t)Bs * 12288 > ws_size) Bs >>= 1;
    int nslice = B / Bs;
    int M = Bs * 4;

    bf16* R1 = (bf16*)sl;                       // h1 FT [M,1024]; then h3 FT [M,256]
    bf16* R2 = R1 + (size_t)Bs * 4096;          // h2 FT [M,512]; then h4 FT [M,256]

    // one-shot prep: ssq zero + all weight transforms + edge setup
    hipLaunchKernelGGL(k_prep, dim3(6273), dim3(256), 0, stream,
                       ei, gmat, W1, Wl2, Wr2, Wl3, Wr3, Wl4, Wr4,
                       Wt1, Wt2, Wt3, Wt4, (float4*)ssqb);

    for (int s = 0; s < nslice; s++) {
        const float* xs = x + (size_t)s * Bs * 256;
        float* ssqs = ssqb + (size_t)s * 3 * M;       // disjoint per slice
        // L1 GCN: h1 = relu(mix(x@W1) + b1)  K=64; A = fp32 x (fused cast)
        hipLaunchKernelGGL(gemm_gcn, dim3(4, M / 128), dim3(256), 0, stream,
                           xs, Wt1, b1, R1, 1024, gmat);
        // L2 SAGE: relu(h2_un) (F=512) + ssq2   N=1024, K=1024
        hipLaunchKernelGGL(gemm_sage, dim3(4, M / 128), dim3(256), 0, stream,
                           R1, 1024, Wt2, bl2, R2, 1024, gmat + 16, ssqs,
                           (const float*)nullptr);
        // L3 SAGE: relu(h3_un) (F=256) into R1, input scaled by inv(ssq2)
        hipLaunchKernelGGL(gemm_sage, dim3(2, M / 128), dim3(256), 0, stream,
                           R2, 512, Wt3, bl3, R1, 512, gmat + 16, ssqs + M,
                           (const float*)ssqs);
        // L4 SAGE: relu(h4_un) (F=256) into R2, input scaled by inv(ssq3)
        hipLaunchKernelGGL(gemm_sage, dim3(2, M / 128), dim3(256), 0, stream,
                           R1, 256, Wt4, bl4, R2, 512, gmat + 16, ssqs + 2 * M,
                           (const float*)(ssqs + M));
        // FC + softmax with fused h4 norm (512-thread blocks, 32 waves/CU)
        hipLaunchKernelGGL(fc_softmax, dim3(512), dim3(512), 0, stream,
                           (const bf16x8*)R2, ssqs + 2 * M, Wfc, bfc,
                           out + (size_t)s * Bs * 10, Bs);
    }
}